// Round 1
// baseline (1355.732 us; speedup 1.0000x reference)
//
#include <hip/hip_runtime.h>

#define GDIM 7
#define NN 49            // nodes per graph
#define FDIM 1024
#define HD 8
#define CD 128
#define ODIM 256
#define NC 14
#define MAXE 12          // max incoming edges: 8 spatial + 3 knn + self

// ---------------------------------------------------------------------------
// K1: relu + transpose  feat[B,1024,49] -> X[B*49,1024]
// ---------------------------------------------------------------------------
__global__ void __launch_bounds__(256) relu_transpose_kernel(
    const float* __restrict__ F, float* __restrict__ X) {
  const int b  = blockIdx.x >> 4;          // 16 f-chunks of 64
  const int f0 = (blockIdx.x & 15) << 6;
  const int tid = threadIdx.x;
  __shared__ float lds[64 * NN];
  const float* src = F + (size_t)b * FDIM * NN + (size_t)f0 * NN;
  // contiguous 64*49 span
  for (int idx = tid; idx < 64 * NN; idx += 256) lds[idx] = src[idx];
  __syncthreads();
  for (int pass = 0; pass < 13; pass++) {
    int n = pass * 4 + (tid >> 6);
    int fi = tid & 63;
    if (n < NN) {
      float v = lds[fi * NN + n];
      X[((size_t)b * NN + n) * FDIM + f0 + fi] = v > 0.f ? v : 0.f;
    }
  }
}

// ---------------------------------------------------------------------------
// K2: per-graph Gram matrix + top-3 kNN (stable, matches jax.lax.top_k ties)
// ---------------------------------------------------------------------------
#define PPT 10  // ceil(49*49 / 256)
__global__ void __launch_bounds__(256) knn_kernel(
    const float* __restrict__ X, int* __restrict__ knn) {
  const int b = blockIdx.x, tid = threadIdx.x;
  __shared__ float xs[NN * 65];    // chunk [49][64] padded
  __shared__ float gram[NN * 50];  // [49][49] padded
  const float* Xb = X + (size_t)b * NN * FDIM;

  int pn[PPT], pm[PPT];
  float acc[PPT];
#pragma unroll
  for (int p = 0; p < PPT; p++) {
    int pr = tid + p * 256;
    if (pr >= NN * NN) pr = 0;
    pn[p] = pr / NN;
    pm[p] = pr % NN;
    acc[p] = 0.f;
  }
  for (int c0 = 0; c0 < FDIM; c0 += 64) {
    __syncthreads();
    for (int idx = tid; idx < NN * 64; idx += 256) {
      int n = idx >> 6, j = idx & 63;
      xs[n * 65 + j] = Xb[(size_t)n * FDIM + c0 + j];
    }
    __syncthreads();
#pragma unroll
    for (int p = 0; p < PPT; p++) {
      const float* rn = &xs[pn[p] * 65];
      const float* rm = &xs[pm[p] * 65];
      float a = 0.f;
#pragma unroll 8
      for (int j = 0; j < 64; j++) a += rn[j] * rm[j];
      acc[p] += a;
    }
  }
#pragma unroll
  for (int p = 0; p < PPT; p++) {
    int pr = tid + p * 256;
    if (pr < NN * NN) gram[pn[p] * 50 + pm[p]] = acc[p];
  }
  __syncthreads();
  if (tid < NN) {
    const int n = tid;
    const float sqn = gram[n * 50 + n];
    float d0 = 1e30f, d1 = 1e30f, d2 = 1e30f;
    int i0 = 0, i1 = 0, i2 = 0;
    for (int m = 0; m < NN; m++) {
      if (m == n) continue;
      float d = sqn + gram[m * 50 + m] - 2.f * gram[n * 50 + m];
      if (d < d0)      { d2=d1; i2=i1; d1=d0; i1=i0; d0=d; i0=m; }
      else if (d < d1) { d2=d1; i2=i1; d1=d;  i1=m; }
      else if (d < d2) { d2=d;  i2=m; }
    }
    knn[((size_t)b * NN + n) * 3 + 0] = i0;
    knn[((size_t)b * NN + n) * 3 + 1] = i1;
    knn[((size_t)b * NN + n) * 3 + 2] = i2;
  }
}

// ---------------------------------------------------------------------------
// K3/K5: tiled fp32 GEMM  C[M,N] = A[M,K] @ B[K,N]   (M%128==0, N%128==0, K%8==0)
// ---------------------------------------------------------------------------
__global__ void __launch_bounds__(256) gemm_f32(
    const float* __restrict__ A, const float* __restrict__ B,
    float* __restrict__ C, int M, int N, int K) {
  const int BM = 128, BN = 128, BK = 8, TM = 8, TN = 8;
  __shared__ float As[BK][BM];
  __shared__ float Bs[BK][BN];
  const int tid = threadIdx.x;
  const int nbx = N / BN;
  const int bx = blockIdx.x % nbx;
  const int by = blockIdx.x / nbx;
  const int row0 = by * BM, col0 = bx * BN;
  const int tx = tid & 15, ty = tid >> 4;
  const int ar = tid >> 1, ac = (tid & 1) * 4;
  const int br = tid >> 5, bc = (tid & 31) * 4;
  float acc[TM][TN] = {};
  for (int k0 = 0; k0 < K; k0 += BK) {
    float4 av = *(const float4*)&A[(size_t)(row0 + ar) * K + k0 + ac];
    float4 bv = *(const float4*)&B[(size_t)(k0 + br) * N + col0 + bc];
    __syncthreads();
    As[ac + 0][ar] = av.x; As[ac + 1][ar] = av.y;
    As[ac + 2][ar] = av.z; As[ac + 3][ar] = av.w;
    *(float4*)&Bs[br][bc] = bv;
    __syncthreads();
#pragma unroll
    for (int kk = 0; kk < BK; kk++) {
      float4 a0 = *(const float4*)&As[kk][ty * TM];
      float4 a1 = *(const float4*)&As[kk][ty * TM + 4];
      float4 b0 = *(const float4*)&Bs[kk][tx * TN];
      float4 b1 = *(const float4*)&Bs[kk][tx * TN + 4];
      float ra[TM] = {a0.x,a0.y,a0.z,a0.w,a1.x,a1.y,a1.z,a1.w};
      float rb[TN] = {b0.x,b0.y,b0.z,b0.w,b1.x,b1.y,b1.z,b1.w};
#pragma unroll
      for (int i = 0; i < TM; i++)
#pragma unroll
        for (int j = 0; j < TN; j++) acc[i][j] += ra[i] * rb[j];
    }
  }
#pragma unroll
  for (int i = 0; i < TM; i++) {
#pragma unroll
    for (int j = 0; j < TN; j += 4) {
      float4 v = {acc[i][j], acc[i][j+1], acc[i][j+2], acc[i][j+3]};
      *(float4*)&C[(size_t)(row0 + ty * TM + i) * N + col0 + tx * TN + j] = v;
    }
  }
}

// ---------------------------------------------------------------------------
// K4: attention layer 1 (H=8, C=128) fused: es/ed dots, per-dst softmax,
//     aggregate, +b1, elu.  Z = elu(agg + b1), one block per graph.
// ---------------------------------------------------------------------------
__global__ void __launch_bounds__(256) attn1_kernel(
    const float* __restrict__ H, const int* __restrict__ knn,
    const float* __restrict__ a_src, const float* __restrict__ a_dst,
    const float* __restrict__ b1, float* __restrict__ Z) {
  const int b = blockIdx.x, tid = threadIdx.x;
  __shared__ float es[NN][HD], ed[NN][HD];
  __shared__ float alpha[NN][MAXE][HD];
  __shared__ int srcs[NN][MAXE];
  __shared__ int cnt[NN];
  const float* Hb = H + (size_t)b * NN * FDIM;

  for (int p = tid; p < NN * HD; p += 256) {
    int n = p >> 3, h = p & 7;
    const float* hr = Hb + (size_t)n * FDIM + h * CD;
    float s1 = 0.f, s2 = 0.f;
    for (int c = 0; c < CD; c += 4) {
      float4 hv = *(const float4*)&hr[c];
      float4 as = *(const float4*)&a_src[h * CD + c];
      float4 ad = *(const float4*)&a_dst[h * CD + c];
      s1 += hv.x*as.x + hv.y*as.y + hv.z*as.z + hv.w*as.w;
      s2 += hv.x*ad.x + hv.y*ad.y + hv.z*ad.z + hv.w*ad.w;
    }
    es[n][h] = s1; ed[n][h] = s2;
  }
  if (tid < NN) {
    int i = tid, r = i / GDIM, c = i % GDIM, k = 0;
    for (int dr = -1; dr <= 1; dr++)
      for (int dc = -1; dc <= 1; dc++) {
        if (dr == 0 && dc == 0) continue;
        int rr = r + dr, cc = c + dc;
        if (rr >= 0 && rr < GDIM && cc >= 0 && cc < GDIM)
          srcs[i][k++] = rr * GDIM + cc;
      }
    srcs[i][k++] = knn[((size_t)b * NN + i) * 3 + 0];
    srcs[i][k++] = knn[((size_t)b * NN + i) * 3 + 1];
    srcs[i][k++] = knn[((size_t)b * NN + i) * 3 + 2];
    srcs[i][k++] = i;   // self loop
    cnt[i] = k;
  }
  __syncthreads();
  for (int p = tid; p < NN * HD; p += 256) {
    int i = p >> 3, h = p & 7;
    int k = cnt[i];
    float e[MAXE];
    float m = -1e30f;
#pragma unroll
    for (int j = 0; j < MAXE; j++) {
      if (j < k) {
        float v = es[srcs[i][j]][h] + ed[i][h];
        v = v >= 0.f ? v : 0.2f * v;   // leaky_relu 0.2
        e[j] = v;
        m = fmaxf(m, v);
      }
    }
    float denom = 0.f;
#pragma unroll
    for (int j = 0; j < MAXE; j++) {
      if (j < k) { e[j] = expf(e[j] - m); denom += e[j]; }
    }
    float inv = 1.f / fmaxf(denom, 1e-16f);
#pragma unroll
    for (int j = 0; j < MAXE; j++) {
      if (j < k) alpha[i][j][h] = e[j] * inv;
    }
  }
  __syncthreads();
  for (int i = 0; i < NN; i++) {
    int k = cnt[i];
    for (int f = tid; f < FDIM; f += 256) {
      int h = f >> 7;
      float a = 0.f;
#pragma unroll
      for (int j = 0; j < MAXE; j++) {
        if (j < k) a += alpha[i][j][h] * Hb[(size_t)srcs[i][j] * FDIM + f];
      }
      float z = a + b1[f];
      z = z > 0.f ? z : expm1f(z);     // elu
      Z[((size_t)b * NN + i) * FDIM + f] = z;
    }
  }
}

// ---------------------------------------------------------------------------
// K6: attention layer 2 (H=1, C=256) + elu + global mean pool -> pooled[B,256]
// ---------------------------------------------------------------------------
__global__ void __launch_bounds__(256) attn2_pool_kernel(
    const float* __restrict__ H2, const int* __restrict__ knn,
    const float* __restrict__ a_src, const float* __restrict__ a_dst,
    const float* __restrict__ b2, float* __restrict__ pooled) {
  const int b = blockIdx.x, tid = threadIdx.x;
  __shared__ float es[NN], ed[NN];
  __shared__ float alpha[NN][MAXE];
  __shared__ int srcs[NN][MAXE];
  __shared__ int cnt[NN];
  const float* Hb = H2 + (size_t)b * NN * ODIM;

  if (tid < NN) {
    const float* hr = Hb + (size_t)tid * ODIM;
    float s1 = 0.f, s2 = 0.f;
    for (int c = 0; c < ODIM; c += 4) {
      float4 hv = *(const float4*)&hr[c];
      float4 as = *(const float4*)&a_src[c];
      float4 ad = *(const float4*)&a_dst[c];
      s1 += hv.x*as.x + hv.y*as.y + hv.z*as.z + hv.w*as.w;
      s2 += hv.x*ad.x + hv.y*ad.y + hv.z*ad.z + hv.w*ad.w;
    }
    es[tid] = s1; ed[tid] = s2;
    int i = tid, r = i / GDIM, c2 = i % GDIM, k = 0;
    for (int dr = -1; dr <= 1; dr++)
      for (int dc = -1; dc <= 1; dc++) {
        if (dr == 0 && dc == 0) continue;
        int rr = r + dr, cc = c2 + dc;
        if (rr >= 0 && rr < GDIM && cc >= 0 && cc < GDIM)
          srcs[i][k++] = rr * GDIM + cc;
      }
    srcs[i][k++] = knn[((size_t)b * NN + i) * 3 + 0];
    srcs[i][k++] = knn[((size_t)b * NN + i) * 3 + 1];
    srcs[i][k++] = knn[((size_t)b * NN + i) * 3 + 2];
    srcs[i][k++] = i;
    cnt[i] = k;
  }
  __syncthreads();
  if (tid < NN) {
    int i = tid, k = cnt[i];
    float e[MAXE];
    float m = -1e30f;
#pragma unroll
    for (int j = 0; j < MAXE; j++) {
      if (j < k) {
        float v = es[srcs[i][j]] + ed[i];
        v = v >= 0.f ? v : 0.2f * v;
        e[j] = v;
        m = fmaxf(m, v);
      }
    }
    float denom = 0.f;
#pragma unroll
    for (int j = 0; j < MAXE; j++) {
      if (j < k) { e[j] = expf(e[j] - m); denom += e[j]; }
    }
    float inv = 1.f / fmaxf(denom, 1e-16f);
#pragma unroll
    for (int j = 0; j < MAXE; j++) {
      if (j < k) alpha[i][j] = e[j] * inv;
    }
  }
  __syncthreads();
  // aggregate + elu + mean pool; thread = channel
  float psum = 0.f;
  const int c = tid;  // 0..255
  for (int i = 0; i < NN; i++) {
    int k = cnt[i];
    float a = 0.f;
#pragma unroll
    for (int j = 0; j < MAXE; j++) {
      if (j < k) a += alpha[i][j] * Hb[(size_t)srcs[i][j] * ODIM + c];
    }
    float z = a + b2[c];
    z = z > 0.f ? z : expm1f(z);
    psum += z;
  }
  pooled[(size_t)b * ODIM + c] = psum * (1.f / 49.f);
}

// ---------------------------------------------------------------------------
// K7: classifier  out = relu(pooled@Wc1+bc1)@Wc2+bc2
// ---------------------------------------------------------------------------
__global__ void __launch_bounds__(256) classifier_kernel(
    const float* __restrict__ pooled, const float* __restrict__ Wc1,
    const float* __restrict__ bc1, const float* __restrict__ Wc2,
    const float* __restrict__ bc2, float* __restrict__ out) {
  const int b = blockIdx.x, tid = threadIdx.x;
  __shared__ float p[ODIM];
  __shared__ float t[ODIM];
  p[tid] = pooled[(size_t)b * ODIM + tid];
  __syncthreads();
  float a = bc1[tid];
  for (int c = 0; c < ODIM; c++) a += p[c] * Wc1[(size_t)c * ODIM + tid];
  t[tid] = a > 0.f ? a : 0.f;
  __syncthreads();
  if (tid < NC) {
    float o = bc2[tid];
    for (int j = 0; j < ODIM; j++) o += t[j] * Wc2[(size_t)j * NC + tid];
    out[(size_t)b * NC + tid] = o;
  }
}

// ---------------------------------------------------------------------------
extern "C" void kernel_launch(void* const* d_in, const int* in_sizes, int n_in,
                              void* d_out, int out_size, void* d_ws, size_t ws_size,
                              hipStream_t stream) {
  const float* feat   = (const float*)d_in[0];
  const float* W1     = (const float*)d_in[1];
  const float* a_src1 = (const float*)d_in[2];
  const float* a_dst1 = (const float*)d_in[3];
  const float* b1     = (const float*)d_in[4];
  const float* W2     = (const float*)d_in[5];
  const float* a_src2 = (const float*)d_in[6];
  const float* a_dst2 = (const float*)d_in[7];
  const float* b2     = (const float*)d_in[8];
  const float* Wc1    = (const float*)d_in[9];
  const float* bc1    = (const float*)d_in[10];
  const float* Wc2    = (const float*)d_in[11];
  const float* bc2    = (const float*)d_in[12];

  const int B = in_sizes[0] / (FDIM * NN);   // 256
  const int M = B * NN;                       // 12544

  const size_t xElems = (size_t)M * FDIM;     // 12,845,056
  float* X      = (float*)d_ws;               // X, later Z1
  float* H1     = X + xElems;                 // H1, later H2
  int*   knn    = (int*)(H1 + xElems);
  float* pooled = (float*)(knn + (size_t)B * NN * 3);

  relu_transpose_kernel<<<B * 16, 256, 0, stream>>>(feat, X);
  knn_kernel<<<B, 256, 0, stream>>>(X, knn);
  // H1 = X @ W1   [M,1024]x[1024,1024]
  gemm_f32<<<(M / 128) * (FDIM / 128), 256, 0, stream>>>(X, W1, H1, M, FDIM, FDIM);
  // Z1 (into X buffer) = attn1(H1)
  attn1_kernel<<<B, 256, 0, stream>>>(H1, knn, a_src1, a_dst1, b1, X);
  // H2 (into H1 buffer) = Z1 @ W2   [M,1024]x[1024,256]
  gemm_f32<<<(M / 128) * (ODIM / 128), 256, 0, stream>>>(X, W2, H1, M, ODIM, FDIM);
  // pooled = attn2 + mean pool
  attn2_pool_kernel<<<B, 256, 0, stream>>>(H1, knn, a_src2, a_dst2, b2, pooled);
  classifier_kernel<<<B, 256, 0, stream>>>(pooled, Wc1, bc1, Wc2, bc2, (float*)d_out);
}

// Round 4
// 547.551 us; speedup vs baseline: 2.4760x; 2.4760x over previous
//
#include <hip/hip_runtime.h>

#define GDIM 7
#define NN 49            // nodes per graph
#define FDIM 1024
#define HD 8
#define CD 128
#define ODIM 256
#define NC 14
#define MAXE 12          // max incoming edges: 8 spatial + 3 knn + self

typedef __attribute__((ext_vector_type(4))) float f32x4;
typedef __attribute__((ext_vector_type(8))) short s16x8;

struct us4 { unsigned short x, y, z, w; };

__device__ __forceinline__ unsigned short f2bf(float x) {
  unsigned u = __float_as_uint(x);
  return (unsigned short)((u + 0x7fffu + ((u >> 16) & 1u)) >> 16);  // RNE
}
__device__ __forceinline__ float bf2f(unsigned short h) {
  return __uint_as_float((unsigned)h << 16);
}

#define GLOAD_LDS16(g, l)                                          \
  __builtin_amdgcn_global_load_lds(                                \
      (const __attribute__((address_space(1))) void*)(g),          \
      (__attribute__((address_space(3))) void*)(l), 16, 0, 0)

// ---------------------------------------------------------------------------
// K1: relu + transpose  feat[B,1024,49] -> X fp32 + Xh/Xl bf16 split [B*49,1024]
// ---------------------------------------------------------------------------
__global__ void __launch_bounds__(256) relu_transpose_kernel(
    const float* __restrict__ F, float* __restrict__ X,
    unsigned short* __restrict__ Xh, unsigned short* __restrict__ Xl) {
  const int b  = blockIdx.x >> 4;          // 16 f-chunks of 64
  const int f0 = (blockIdx.x & 15) << 6;
  const int tid = threadIdx.x;
  __shared__ float lds[64 * NN];
  const float* src = F + (size_t)b * FDIM * NN + (size_t)f0 * NN;
  for (int idx = tid; idx < 64 * NN; idx += 256) lds[idx] = src[idx];
  __syncthreads();
  for (int pass = 0; pass < 13; pass++) {
    int n = pass * 4 + (tid >> 6);
    int fi = tid & 63;
    if (n < NN) {
      float v = lds[fi * NN + n];
      v = v > 0.f ? v : 0.f;
      size_t o = ((size_t)b * NN + n) * FDIM + f0 + fi;
      X[o] = v;
      unsigned short h = f2bf(v);
      Xh[o] = h;
      Xl[o] = f2bf(v - bf2f(h));
    }
  }
}

// ---------------------------------------------------------------------------
// K2: per-graph Gram matrix + top-3 kNN (fp32, stable tie-break)
// ---------------------------------------------------------------------------
#define PPT 10  // ceil(49*49 / 256)
__global__ void __launch_bounds__(256) knn_kernel(
    const float* __restrict__ X, int* __restrict__ knn) {
  const int b = blockIdx.x, tid = threadIdx.x;
  __shared__ float xs[NN * 65];
  __shared__ float gram[NN * 50];
  const float* Xb = X + (size_t)b * NN * FDIM;

  int pn[PPT], pm[PPT];
  float acc[PPT];
#pragma unroll
  for (int p = 0; p < PPT; p++) {
    int pr = tid + p * 256;
    if (pr >= NN * NN) pr = 0;
    pn[p] = pr / NN;
    pm[p] = pr % NN;
    acc[p] = 0.f;
  }
  for (int c0 = 0; c0 < FDIM; c0 += 64) {
    __syncthreads();
    for (int idx = tid; idx < NN * 64; idx += 256) {
      int n = idx >> 6, j = idx & 63;
      xs[n * 65 + j] = Xb[(size_t)n * FDIM + c0 + j];
    }
    __syncthreads();
#pragma unroll
    for (int p = 0; p < PPT; p++) {
      const float* rn = &xs[pn[p] * 65];
      const float* rm = &xs[pm[p] * 65];
      float a = 0.f;
#pragma unroll 8
      for (int j = 0; j < 64; j++) a += rn[j] * rm[j];
      acc[p] += a;
    }
  }
#pragma unroll
  for (int p = 0; p < PPT; p++) {
    int pr = tid + p * 256;
    if (pr < NN * NN) gram[pn[p] * 50 + pm[p]] = acc[p];
  }
  __syncthreads();
  if (tid < NN) {
    const int n = tid;
    const float sqn = gram[n * 50 + n];
    float d0 = 1e30f, d1 = 1e30f, d2 = 1e30f;
    int i0 = 0, i1 = 0, i2 = 0;
    for (int m = 0; m < NN; m++) {
      if (m == n) continue;
      float d = sqn + gram[m * 50 + m] - 2.f * gram[n * 50 + m];
      if (d < d0)      { d2=d1; i2=i1; d1=d0; i1=i0; d0=d; i0=m; }
      else if (d < d1) { d2=d1; i2=i1; d1=d;  i1=m; }
      else if (d < d2) { d2=d;  i2=m; }
    }
    knn[((size_t)b * NN + n) * 3 + 0] = i0;
    knn[((size_t)b * NN + n) * 3 + 1] = i1;
    knn[((size_t)b * NN + n) * 3 + 2] = i2;
  }
}

// ---------------------------------------------------------------------------
// K-w: weight convert + transpose  W[K,N] fp32 -> WhT/WlT[N,K] bf16 split
// ---------------------------------------------------------------------------
__global__ void __launch_bounds__(256) wconvT_kernel(
    const float* __restrict__ W, int K, int N,
    unsigned short* __restrict__ WhT, unsigned short* __restrict__ WlT) {
  __shared__ float t[64][65];
  const int nbx = N >> 6;
  const int bx = blockIdx.x % nbx, by = blockIdx.x / nbx;
  const int r0 = by << 6, c0 = bx << 6;
  const int tid = threadIdx.x;
#pragma unroll
  for (int i = 0; i < 16; i++) {
    int r = i * 4 + (tid >> 6), c = tid & 63;
    t[r][c] = W[(size_t)(r0 + r) * N + c0 + c];
  }
  __syncthreads();
#pragma unroll
  for (int i = 0; i < 16; i++) {
    int n = i * 4 + (tid >> 6);   // row of WT (= col of W)
    int k = tid & 63;             // col of WT (= row of W)
    float x = t[k][n];
    unsigned short h = f2bf(x);
    size_t o = (size_t)(c0 + n) * K + r0 + k;
    WhT[o] = h;
    WlT[o] = f2bf(x - bf2f(h));
  }
}

// ---------------------------------------------------------------------------
// K3/K5: bf16x3-split MFMA GEMM  C[M,N] = (Ah+Al)@(Bh+Bl)^TT
//   A as [M,K] bf16 hi/lo, B pre-transposed [N,K] bf16 hi/lo.
//   128x128 tile, BK=32, 4 waves, m97-style global_load_lds staging.
// ---------------------------------------------------------------------------
__global__ void __launch_bounds__(256) gemm_bf16x3(
    const unsigned short* __restrict__ A_h, const unsigned short* __restrict__ A_l,
    const unsigned short* __restrict__ BT_h, const unsigned short* __restrict__ BT_l,
    float* __restrict__ C, int M, int N, int K) {
  __shared__ unsigned short sAh[128][32], sAl[128][32];
  __shared__ unsigned short sBh[128][32], sBl[128][32];
  const int tid = threadIdx.x;
  const int w = tid >> 6, lane = tid & 63;
  const int nbx = N >> 7;
  const int bx = blockIdx.x % nbx, by = blockIdx.x / nbx;
  const int row0 = by << 7, col0 = bx << 7;
  const int wr = (w >> 1) << 6, wc = (w & 1) << 6;   // wave quadrant
  const int srow = lane >> 2, schk = lane & 3;       // staging: row/16B-chunk
  const int fr = lane & 15, fk = (lane >> 4) << 3;   // fragment: row, k-base

  f32x4 acc[4][4];
#pragma unroll
  for (int m = 0; m < 4; m++)
#pragma unroll
    for (int n = 0; n < 4; n++) acc[m][n] = (f32x4){0.f, 0.f, 0.f, 0.f};

  for (int k0 = 0; k0 < K; k0 += 32) {
    __syncthreads();
#pragma unroll
    for (int i = 0; i < 2; i++) {
      const int rbase = (w << 5) + (i << 4);         // wave-uniform segment base
      const int gr = rbase + srow;                   // per-lane row in tile
      const size_t ga = (size_t)(row0 + gr) * K + k0 + (schk << 3);
      GLOAD_LDS16(A_h + ga, &sAh[rbase][0]);
      GLOAD_LDS16(A_l + ga, &sAl[rbase][0]);
      const size_t gb = (size_t)(col0 + gr) * K + k0 + (schk << 3);
      GLOAD_LDS16(BT_h + gb, &sBh[rbase][0]);
      GLOAD_LDS16(BT_l + gb, &sBl[rbase][0]);
    }
    __syncthreads();
    s16x8 ah[4], al[4], bh[4], bl[4];
#pragma unroll
    for (int m = 0; m < 4; m++) {
      ah[m] = *(const s16x8*)&sAh[wr + (m << 4) + fr][fk];
      al[m] = *(const s16x8*)&sAl[wr + (m << 4) + fr][fk];
      bh[m] = *(const s16x8*)&sBh[wc + (m << 4) + fr][fk];
      bl[m] = *(const s16x8*)&sBl[wc + (m << 4) + fr][fk];
    }
#pragma unroll
    for (int m = 0; m < 4; m++)
#pragma unroll
      for (int n = 0; n < 4; n++) {
        acc[m][n] = __builtin_amdgcn_mfma_f32_16x16x32_bf16(ah[m], bh[n], acc[m][n], 0, 0, 0);
        acc[m][n] = __builtin_amdgcn_mfma_f32_16x16x32_bf16(ah[m], bl[n], acc[m][n], 0, 0, 0);
        acc[m][n] = __builtin_amdgcn_mfma_f32_16x16x32_bf16(al[m], bh[n], acc[m][n], 0, 0, 0);
      }
  }
  const int crow = (lane >> 4) << 2, ccol = lane & 15;
#pragma unroll
  for (int m = 0; m < 4; m++)
#pragma unroll
    for (int n = 0; n < 4; n++)
#pragma unroll
      for (int v = 0; v < 4; v++)
        C[(size_t)(row0 + wr + (m << 4) + crow + v) * N + col0 + wc + (n << 4) + ccol] =
            acc[m][n][v];
}

// ---------------------------------------------------------------------------
// K4a: attn1 prep — per graph: es/ed dots, edge lists, softmax alphas
// ---------------------------------------------------------------------------
__global__ void __launch_bounds__(256) attn1_prep(
    const float* __restrict__ H, const int* __restrict__ knn,
    const float* __restrict__ a_src, const float* __restrict__ a_dst,
    int* __restrict__ srcs_g, int* __restrict__ cnt_g,
    float* __restrict__ alpha_g) {
  const int b = blockIdx.x, tid = threadIdx.x;
  __shared__ float es[NN][HD], ed[NN][HD];
  __shared__ int srcs[NN][MAXE];
  __shared__ int cnt[NN];
  const float* Hb = H + (size_t)b * NN * FDIM;

  for (int p = tid; p < NN * HD; p += 256) {
    int n = p >> 3, h = p & 7;
    const float* hr = Hb + (size_t)n * FDIM + h * CD;
    float s1 = 0.f, s2 = 0.f;
    for (int c = 0; c < CD; c += 4) {
      float4 hv = *(const float4*)&hr[c];
      float4 as = *(const float4*)&a_src[h * CD + c];
      float4 ad = *(const float4*)&a_dst[h * CD + c];
      s1 += hv.x*as.x + hv.y*as.y + hv.z*as.z + hv.w*as.w;
      s2 += hv.x*ad.x + hv.y*ad.y + hv.z*ad.z + hv.w*ad.w;
    }
    es[n][h] = s1; ed[n][h] = s2;
  }
  if (tid < NN) {
    int i = tid, r = i / GDIM, c = i % GDIM, k = 0;
    for (int dr = -1; dr <= 1; dr++)
      for (int dc = -1; dc <= 1; dc++) {
        if (dr == 0 && dc == 0) continue;
        int rr = r + dr, cc = c + dc;
        if (rr >= 0 && rr < GDIM && cc >= 0 && cc < GDIM)
          srcs[i][k++] = rr * GDIM + cc;
      }
    srcs[i][k++] = knn[((size_t)b * NN + i) * 3 + 0];
    srcs[i][k++] = knn[((size_t)b * NN + i) * 3 + 1];
    srcs[i][k++] = knn[((size_t)b * NN + i) * 3 + 2];
    srcs[i][k++] = i;   // self loop
    cnt[i] = k;
    cnt_g[(size_t)b * NN + i] = k;
    for (int j = 0; j < MAXE; j++)
      srcs_g[((size_t)b * NN + i) * MAXE + j] = srcs[i][j < k ? j : 0];
  }
  __syncthreads();
  for (int p = tid; p < NN * HD; p += 256) {
    int i = p >> 3, h = p & 7;
    int k = cnt[i];
    float e[MAXE];
    float m = -1e30f;
#pragma unroll
    for (int j = 0; j < MAXE; j++) {
      if (j < k) {
        float v = es[srcs[i][j]][h] + ed[i][h];
        v = v >= 0.f ? v : 0.2f * v;   // leaky_relu 0.2
        e[j] = v;
        m = fmaxf(m, v);
      }
    }
    float denom = 0.f;
#pragma unroll
    for (int j = 0; j < MAXE; j++) {
      if (j < k) { e[j] = expf(e[j] - m); denom += e[j]; }
    }
    float inv = 1.f / fmaxf(denom, 1e-16f);
#pragma unroll
    for (int j = 0; j < MAXE; j++) {
      if (j < k)
        alpha_g[(((size_t)b * NN + i) * MAXE + j) * HD + h] = e[j] * inv;
    }
  }
}

// ---------------------------------------------------------------------------
// K4b: attn1 aggregation — block per (graph,node); emits Z1 as bf16 hi/lo
// ---------------------------------------------------------------------------
__global__ void __launch_bounds__(256) attn1_agg(
    const float* __restrict__ H, const int* __restrict__ srcs_g,
    const int* __restrict__ cnt_g, const float* __restrict__ alpha_g,
    const float* __restrict__ b1,
    unsigned short* __restrict__ Zh, unsigned short* __restrict__ Zl) {
  const int bid = blockIdx.x;          // = b*NN + i
  const int b = bid / NN;
  const int tid = threadIdx.x;
  __shared__ float al[MAXE][HD];
  __shared__ int ss[MAXE];
  const int k = cnt_g[bid];
  if (tid < MAXE * HD) al[tid >> 3][tid & 7] = alpha_g[(size_t)bid * MAXE * HD + tid];
  if (tid < MAXE) ss[tid] = srcs_g[(size_t)bid * MAXE + tid];
  __syncthreads();
  const float4* Hb = (const float4*)(H + (size_t)b * NN * FDIM);
  const int h = tid >> 5;
  float4 acc = ((const float4*)b1)[tid];
  for (int j = 0; j < k; j++) {
    float a = al[j][h];
    float4 v = Hb[(size_t)ss[j] * (FDIM / 4) + tid];
    acc.x += a * v.x; acc.y += a * v.y; acc.z += a * v.z; acc.w += a * v.w;
  }
  acc.x = acc.x > 0.f ? acc.x : expm1f(acc.x);
  acc.y = acc.y > 0.f ? acc.y : expm1f(acc.y);
  acc.z = acc.z > 0.f ? acc.z : expm1f(acc.z);
  acc.w = acc.w > 0.f ? acc.w : expm1f(acc.w);
  us4 hv, lv;
  hv.x = f2bf(acc.x); lv.x = f2bf(acc.x - bf2f(hv.x));
  hv.y = f2bf(acc.y); lv.y = f2bf(acc.y - bf2f(hv.y));
  hv.z = f2bf(acc.z); lv.z = f2bf(acc.z - bf2f(hv.z));
  hv.w = f2bf(acc.w); lv.w = f2bf(acc.w - bf2f(hv.w));
  *(us4*)&Zh[(size_t)bid * FDIM + (tid << 2)] = hv;
  *(us4*)&Zl[(size_t)bid * FDIM + (tid << 2)] = lv;
}

// ---------------------------------------------------------------------------
// K6a: attn2 prep — per graph: es/ed (H=1,C=256), softmax alphas
// ---------------------------------------------------------------------------
__global__ void __launch_bounds__(256) attn2_prep(
    const float* __restrict__ H2, const int* __restrict__ srcs_g,
    const int* __restrict__ cnt_g, const float* __restrict__ a_src,
    const float* __restrict__ a_dst, float* __restrict__ alpha_g) {
  const int b = blockIdx.x, tid = threadIdx.x;
  __shared__ float es[NN], ed[NN];
  const float* Hb = H2 + (size_t)b * NN * ODIM;
  if (tid < NN) {
    const float* hr = Hb + (size_t)tid * ODIM;
    float s1 = 0.f, s2 = 0.f;
    for (int c = 0; c < ODIM; c += 4) {
      float4 hv = *(const float4*)&hr[c];
      float4 as = *(const float4*)&a_src[c];
      float4 ad = *(const float4*)&a_dst[c];
      s1 += hv.x*as.x + hv.y*as.y + hv.z*as.z + hv.w*as.w;
      s2 += hv.x*ad.x + hv.y*ad.y + hv.z*ad.z + hv.w*ad.w;
    }
    es[tid] = s1; ed[tid] = s2;
  }
  __syncthreads();
  if (tid < NN) {
    const int i = tid;
    const int k = cnt_g[(size_t)b * NN + i];
    float e[MAXE];
    float m = -1e30f;
#pragma unroll
    for (int j = 0; j < MAXE; j++) {
      if (j < k) {
        int s = srcs_g[((size_t)b * NN + i) * MAXE + j];
        float v = es[s] + ed[i];
        v = v >= 0.f ? v : 0.2f * v;
        e[j] = v;
        m = fmaxf(m, v);
      }
    }
    float denom = 0.f;
#pragma unroll
    for (int j = 0; j < MAXE; j++) {
      if (j < k) { e[j] = expf(e[j] - m); denom += e[j]; }
    }
    float inv = 1.f / fmaxf(denom, 1e-16f);
#pragma unroll
    for (int j = 0; j < MAXE; j++) {
      if (j < k) alpha_g[((size_t)b * NN + i) * MAXE + j] = e[j] * inv;
    }
  }
}

// ---------------------------------------------------------------------------
// K6b: attn2 aggregation — block per (graph,node); thread = channel
// ---------------------------------------------------------------------------
__global__ void __launch_bounds__(256) attn2_agg(
    const float* __restrict__ H2, const int* __restrict__ srcs_g,
    const int* __restrict__ cnt_g, const float* __restrict__ alpha_g,
    const float* __restrict__ b2, float* __restrict__ Z2) {
  const int bid = blockIdx.x;
  const int b = bid / NN;
  const int tid = threadIdx.x;
  __shared__ float al[MAXE];
  __shared__ int ss[MAXE];
  const int k = cnt_g[bid];
  if (tid < MAXE) {
    al[tid] = alpha_g[(size_t)bid * MAXE + tid];
    ss[tid] = srcs_g[(size_t)bid * MAXE + tid];
  }
  __syncthreads();
  const float* Hb = H2 + (size_t)b * NN * ODIM;
  float acc = b2[tid];
  for (int j = 0; j < k; j++)
    acc += al[j] * Hb[(size_t)ss[j] * ODIM + tid];
  acc = acc > 0.f ? acc : expm1f(acc);
  Z2[(size_t)bid * ODIM + tid] = acc;
}

// ---------------------------------------------------------------------------
// K6c: global mean pool
// ---------------------------------------------------------------------------
__global__ void __launch_bounds__(256) pool_kernel(
    const float* __restrict__ Z2, float* __restrict__ pooled) {
  const int b = blockIdx.x, c = threadIdx.x;
  float s = 0.f;
  for (int i = 0; i < NN; i++)
    s += Z2[((size_t)b * NN + i) * ODIM + c];
  pooled[(size_t)b * ODIM + c] = s * (1.f / 49.f);
}

// ---------------------------------------------------------------------------
// K7: classifier
// ---------------------------------------------------------------------------
__global__ void __launch_bounds__(256) classifier_kernel(
    const float* __restrict__ pooled, const float* __restrict__ Wc1,
    const float* __restrict__ bc1, const float* __restrict__ Wc2,
    const float* __restrict__ bc2, float* __restrict__ out) {
  const int b = blockIdx.x, tid = threadIdx.x;
  __shared__ float p[ODIM];
  __shared__ float t[ODIM];
  p[tid] = pooled[(size_t)b * ODIM + tid];
  __syncthreads();
  float a = bc1[tid];
  for (int c = 0; c < ODIM; c++) a += p[c] * Wc1[(size_t)c * ODIM + tid];
  t[tid] = a > 0.f ? a : 0.f;
  __syncthreads();
  if (tid < NC) {
    float o = bc2[tid];
    for (int j = 0; j < ODIM; j++) o += t[j] * Wc2[(size_t)j * NC + tid];
    out[(size_t)b * NC + tid] = o;
  }
}

// ---------------------------------------------------------------------------
extern "C" void kernel_launch(void* const* d_in, const int* in_sizes, int n_in,
                              void* d_out, int out_size, void* d_ws, size_t ws_size,
                              hipStream_t stream) {
  const float* feat   = (const float*)d_in[0];
  const float* W1     = (const float*)d_in[1];
  const float* a_src1 = (const float*)d_in[2];
  const float* a_dst1 = (const float*)d_in[3];
  const float* b1     = (const float*)d_in[4];
  const float* W2     = (const float*)d_in[5];
  const float* a_src2 = (const float*)d_in[6];
  const float* a_dst2 = (const float*)d_in[7];
  const float* b2     = (const float*)d_in[8];
  const float* Wc1    = (const float*)d_in[9];
  const float* bc1    = (const float*)d_in[10];
  const float* Wc2    = (const float*)d_in[11];
  const float* bc2    = (const float*)d_in[12];

  const int B = in_sizes[0] / (FDIM * NN);   // 256
  const int M = B * NN;                       // 12544

  const size_t xE = (size_t)M * FDIM;         // 12,845,056
  float* X  = (float*)d_ws;                   // fp32 X; later H2 (M*ODIM)
  float* H1 = X + xE;                         // fp32 H1; later Z2 (M*ODIM)
  unsigned short* Xh = (unsigned short*)(H1 + xE);  // bf16 hi; later Z1h
  unsigned short* Xl = Xh + xE;                     // bf16 lo; later Z1l
  unsigned short* W1hT = Xl + xE;                   // [1024][1024]
  unsigned short* W1lT = W1hT + (size_t)FDIM * FDIM;
  unsigned short* W2hT = W1lT + (size_t)FDIM * FDIM;  // [256][1024]
  unsigned short* W2lT = W2hT + (size_t)ODIM * FDIM;
  int*   knn    = (int*)(W2lT + (size_t)ODIM * FDIM);
  int*   srcs_g = knn + (size_t)M * 3;
  int*   cnt_g  = srcs_g + (size_t)M * MAXE;
  float* alpha1 = (float*)(cnt_g + M);
  float* alpha2 = alpha1 + (size_t)M * MAXE * HD;
  float* pooled = alpha2 + (size_t)M * MAXE;
  // aliases (producer strictly after last reader of the original)
  float* H2  = X;      // X dead after knn_kernel
  float* Z2  = H1;     // H1 dead after attn1_agg
  unsigned short* Z1h = Xh;  // Xh/Xl dead after gemm1
  unsigned short* Z1l = Xl;

  relu_transpose_kernel<<<B * 16, 256, 0, stream>>>(feat, X, Xh, Xl);
  knn_kernel<<<B, 256, 0, stream>>>(X, knn);
  wconvT_kernel<<<(FDIM / 64) * (FDIM / 64), 256, 0, stream>>>(W1, FDIM, FDIM, W1hT, W1lT);
  wconvT_kernel<<<(FDIM / 64) * (ODIM / 64), 256, 0, stream>>>(W2, FDIM, ODIM, W2hT, W2lT);
  // H1 = X @ W1
  gemm_bf16x3<<<(M / 128) * (FDIM / 128), 256, 0, stream>>>(
      Xh, Xl, W1hT, W1lT, H1, M, FDIM, FDIM);
  // attention layer 1 -> Z1 (bf16 hi/lo into Xh/Xl)
  attn1_prep<<<B, 256, 0, stream>>>(H1, knn, a_src1, a_dst1, srcs_g, cnt_g, alpha1);
  attn1_agg<<<M, 256, 0, stream>>>(H1, srcs_g, cnt_g, alpha1, b1, Z1h, Z1l);
  // H2 = Z1 @ W2  (into X buffer)
  gemm_bf16x3<<<(M / 128) * (ODIM / 128), 256, 0, stream>>>(
      Z1h, Z1l, W2hT, W2lT, H2, M, ODIM, FDIM);
  // attention layer 2 -> Z2 (into H1 buffer)
  attn2_prep<<<B, 256, 0, stream>>>(H2, srcs_g, cnt_g, a_src2, a_dst2, alpha2);
  attn2_agg<<<M, 256, 0, stream>>>(H2, srcs_g, cnt_g, alpha2, b2, Z2);
  pool_kernel<<<B, 256, 0, stream>>>(Z2, pooled);
  classifier_kernel<<<B, 256, 0, stream>>>(pooled, Wc1, bc1, Wc2, bc2, (float*)d_out);
}

// Round 5
// 476.939 us; speedup vs baseline: 2.8426x; 1.1481x over previous
//
#include <hip/hip_runtime.h>

#define GDIM 7
#define NN 49            // nodes per graph
#define FDIM 1024
#define HD 8
#define CD 128
#define ODIM 256
#define NC 14
#define MAXE 12          // max incoming edges: 8 spatial + 3 knn + self

typedef __attribute__((ext_vector_type(4))) float f32x4;
typedef __attribute__((ext_vector_type(8))) short s16x8;

struct us4 { unsigned short x, y, z, w; };

__device__ __forceinline__ unsigned short f2bf(float x) {
  unsigned u = __float_as_uint(x);
  return (unsigned short)((u + 0x7fffu + ((u >> 16) & 1u)) >> 16);  // RNE
}
__device__ __forceinline__ float bf2f(unsigned short h) {
  return __uint_as_float((unsigned)h << 16);
}

#define GLOAD_LDS16(g, l)                                          \
  __builtin_amdgcn_global_load_lds(                                \
      (const __attribute__((address_space(1))) void*)(g),          \
      (__attribute__((address_space(3))) void*)(l), 16, 0, 0)

// ---------------------------------------------------------------------------
// K1: relu + transpose  feat[B,1024,49] -> X fp32 + Xh/Xl bf16 split [B*49,1024]
// ---------------------------------------------------------------------------
__global__ void __launch_bounds__(256) relu_transpose_kernel(
    const float* __restrict__ F, float* __restrict__ X,
    unsigned short* __restrict__ Xh, unsigned short* __restrict__ Xl) {
  const int b  = blockIdx.x >> 4;          // 16 f-chunks of 64
  const int f0 = (blockIdx.x & 15) << 6;
  const int tid = threadIdx.x;
  __shared__ float lds[64 * NN];
  const float* src = F + (size_t)b * FDIM * NN + (size_t)f0 * NN;
  for (int idx = tid; idx < 64 * NN; idx += 256) lds[idx] = src[idx];
  __syncthreads();
  for (int pass = 0; pass < 13; pass++) {
    int n = pass * 4 + (tid >> 6);
    int fi = tid & 63;
    if (n < NN) {
      float v = lds[fi * NN + n];
      v = v > 0.f ? v : 0.f;
      size_t o = ((size_t)b * NN + n) * FDIM + f0 + fi;
      X[o] = v;
      unsigned short h = f2bf(v);
      Xh[o] = h;
      Xl[o] = f2bf(v - bf2f(h));
    }
  }
}

// ---------------------------------------------------------------------------
// K2: Gram slice + top-3 kNN.  grid = B * 7; each block owns 7 dst rows.
//     (round-4 version was 1 block/graph = 1 block/CU -> latency-bound)
// ---------------------------------------------------------------------------
#define KROWS 7   // dst rows per block
__global__ void __launch_bounds__(256) knn_kernel(
    const float* __restrict__ X, int* __restrict__ knn) {
  const int gid = blockIdx.x;
  const int b = gid / KROWS, part = gid % KROWS;
  const int n0 = part * KROWS;
  const int tid = threadIdx.x;
  __shared__ float xs[NN * 65];        // [49][64] chunk, pad 65
  __shared__ float gram[KROWS * 50];   // slice [7][49], pad 50
  __shared__ float sq[NN];
  const float* Xb = X + (size_t)b * NN * FDIM;

  // 343 slice entries -> 2 per thread
  int pn[2], pm[2];
  float acc[2] = {0.f, 0.f};
#pragma unroll
  for (int p = 0; p < 2; p++) {
    int pr = tid + p * 256;
    if (pr >= KROWS * NN) pr = 0;
    pn[p] = pr / NN;     // 0..6 local dst row
    pm[p] = pr % NN;     // 0..48 src row
  }
  float sqacc = 0.f;

  for (int c0 = 0; c0 < FDIM; c0 += 64) {
    __syncthreads();
    for (int idx = tid; idx < NN * 64; idx += 256) {
      int n = idx >> 6, j = idx & 63;
      xs[n * 65 + j] = Xb[(size_t)n * FDIM + c0 + j];
    }
    __syncthreads();
#pragma unroll
    for (int p = 0; p < 2; p++) {
      const float* rn = &xs[(n0 + pn[p]) * 65];
      const float* rm = &xs[pm[p] * 65];
      float a = 0.f;
#pragma unroll 8
      for (int j = 0; j < 64; j++) a += rn[j] * rm[j];
      acc[p] += a;
    }
    if (tid < NN) {
      const float* r = &xs[tid * 65];
      float a = 0.f;
#pragma unroll 8
      for (int j = 0; j < 64; j++) a += r[j] * r[j];
      sqacc += a;
    }
  }
#pragma unroll
  for (int p = 0; p < 2; p++) {
    int pr = tid + p * 256;
    if (pr < KROWS * NN) gram[pn[p] * 50 + pm[p]] = acc[p];
  }
  if (tid < NN) sq[tid] = sqacc;
  __syncthreads();
  if (tid < KROWS) {
    const int n = n0 + tid;
    const float sqn = sq[n];
    float d0 = 1e30f, d1 = 1e30f, d2 = 1e30f;
    int i0 = 0, i1 = 0, i2 = 0;
    for (int m = 0; m < NN; m++) {
      if (m == n) continue;
      float d = sqn + sq[m] - 2.f * gram[tid * 50 + m];
      if (d < d0)      { d2=d1; i2=i1; d1=d0; i1=i0; d0=d; i0=m; }
      else if (d < d1) { d2=d1; i2=i1; d1=d;  i1=m; }
      else if (d < d2) { d2=d;  i2=m; }
    }
    knn[((size_t)b * NN + n) * 3 + 0] = i0;
    knn[((size_t)b * NN + n) * 3 + 1] = i1;
    knn[((size_t)b * NN + n) * 3 + 2] = i2;
  }
}

// ---------------------------------------------------------------------------
// K-w: weight convert + transpose  W[K,N] fp32 -> WhT/WlT[N,K] bf16 split
// ---------------------------------------------------------------------------
__global__ void __launch_bounds__(256) wconvT_kernel(
    const float* __restrict__ W, int K, int N,
    unsigned short* __restrict__ WhT, unsigned short* __restrict__ WlT) {
  __shared__ float t[64][65];
  const int nbx = N >> 6;
  const int bx = blockIdx.x % nbx, by = blockIdx.x / nbx;
  const int r0 = by << 6, c0 = bx << 6;
  const int tid = threadIdx.x;
#pragma unroll
  for (int i = 0; i < 16; i++) {
    int r = i * 4 + (tid >> 6), c = tid & 63;
    t[r][c] = W[(size_t)(r0 + r) * N + c0 + c];
  }
  __syncthreads();
#pragma unroll
  for (int i = 0; i < 16; i++) {
    int n = i * 4 + (tid >> 6);   // row of WT (= col of W)
    int k = tid & 63;             // col of WT (= row of W)
    float x = t[k][n];
    unsigned short h = f2bf(x);
    size_t o = (size_t)(c0 + n) * K + r0 + k;
    WhT[o] = h;
    WlT[o] = f2bf(x - bf2f(h));
  }
}

// ---------------------------------------------------------------------------
// K3/K5: bf16x3-split MFMA GEMM  C[M,N] = (Ah+Al)@(Bh+Bl)
//   A as [M,K] bf16 hi/lo, B pre-transposed [N,K] bf16 hi/lo.
//   128x128 tile, BK=32, 4 waves, m97-style global_load_lds staging.
// ---------------------------------------------------------------------------
__global__ void __launch_bounds__(256) gemm_bf16x3(
    const unsigned short* __restrict__ A_h, const unsigned short* __restrict__ A_l,
    const unsigned short* __restrict__ BT_h, const unsigned short* __restrict__ BT_l,
    float* __restrict__ C, int M, int N, int K) {
  __shared__ unsigned short sAh[128][32], sAl[128][32];
  __shared__ unsigned short sBh[128][32], sBl[128][32];
  const int tid = threadIdx.x;
  const int w = tid >> 6, lane = tid & 63;
  const int nbx = N >> 7;
  const int bx = blockIdx.x % nbx, by = blockIdx.x / nbx;
  const int row0 = by << 7, col0 = bx << 7;
  const int wr = (w >> 1) << 6, wc = (w & 1) << 6;   // wave quadrant
  const int srow = lane >> 2, schk = lane & 3;       // staging: row/16B-chunk
  const int fr = lane & 15, fk = (lane >> 4) << 3;   // fragment: row, k-base

  f32x4 acc[4][4];
#pragma unroll
  for (int m = 0; m < 4; m++)
#pragma unroll
    for (int n = 0; n < 4; n++) acc[m][n] = (f32x4){0.f, 0.f, 0.f, 0.f};

  for (int k0 = 0; k0 < K; k0 += 32) {
    __syncthreads();
#pragma unroll
    for (int i = 0; i < 2; i++) {
      const int rbase = (w << 5) + (i << 4);         // wave-uniform segment base
      const int gr = rbase + srow;                   // per-lane row in tile
      const size_t ga = (size_t)(row0 + gr) * K + k0 + (schk << 3);
      GLOAD_LDS16(A_h + ga, &sAh[rbase][0]);
      GLOAD_LDS16(A_l + ga, &sAl[rbase][0]);
      const size_t gb = (size_t)(col0 + gr) * K + k0 + (schk << 3);
      GLOAD_LDS16(BT_h + gb, &sBh[rbase][0]);
      GLOAD_LDS16(BT_l + gb, &sBl[rbase][0]);
    }
    __syncthreads();
    s16x8 ah[4], al[4], bh[4], bl[4];
#pragma unroll
    for (int m = 0; m < 4; m++) {
      ah[m] = *(const s16x8*)&sAh[wr + (m << 4) + fr][fk];
      al[m] = *(const s16x8*)&sAl[wr + (m << 4) + fr][fk];
      bh[m] = *(const s16x8*)&sBh[wc + (m << 4) + fr][fk];
      bl[m] = *(const s16x8*)&sBl[wc + (m << 4) + fr][fk];
    }
#pragma unroll
    for (int m = 0; m < 4; m++)
#pragma unroll
      for (int n = 0; n < 4; n++) {
        acc[m][n] = __builtin_amdgcn_mfma_f32_16x16x32_bf16(ah[m], bh[n], acc[m][n], 0, 0, 0);
        acc[m][n] = __builtin_amdgcn_mfma_f32_16x16x32_bf16(ah[m], bl[n], acc[m][n], 0, 0, 0);
        acc[m][n] = __builtin_amdgcn_mfma_f32_16x16x32_bf16(al[m], bh[n], acc[m][n], 0, 0, 0);
      }
  }
  const int crow = (lane >> 4) << 2, ccol = lane & 15;
#pragma unroll
  for (int m = 0; m < 4; m++)
#pragma unroll
    for (int n = 0; n < 4; n++)
#pragma unroll
      for (int v = 0; v < 4; v++)
        C[(size_t)(row0 + wr + (m << 4) + crow + v) * N + col0 + wc + (n << 4) + ccol] =
            acc[m][n][v];
}

// ---------------------------------------------------------------------------
// K4a: attn1 prep — per graph: es/ed dots, edge lists, softmax alphas
// ---------------------------------------------------------------------------
__global__ void __launch_bounds__(256) attn1_prep(
    const float* __restrict__ H, const int* __restrict__ knn,
    const float* __restrict__ a_src, const float* __restrict__ a_dst,
    int* __restrict__ srcs_g, int* __restrict__ cnt_g,
    float* __restrict__ alpha_g) {
  const int b = blockIdx.x, tid = threadIdx.x;
  __shared__ float es[NN][HD], ed[NN][HD];
  __shared__ int srcs[NN][MAXE];
  __shared__ int cnt[NN];
  const float* Hb = H + (size_t)b * NN * FDIM;

  for (int p = tid; p < NN * HD; p += 256) {
    int n = p >> 3, h = p & 7;
    const float* hr = Hb + (size_t)n * FDIM + h * CD;
    float s1 = 0.f, s2 = 0.f;
    for (int c = 0; c < CD; c += 4) {
      float4 hv = *(const float4*)&hr[c];
      float4 as = *(const float4*)&a_src[h * CD + c];
      float4 ad = *(const float4*)&a_dst[h * CD + c];
      s1 += hv.x*as.x + hv.y*as.y + hv.z*as.z + hv.w*as.w;
      s2 += hv.x*ad.x + hv.y*ad.y + hv.z*ad.z + hv.w*ad.w;
    }
    es[n][h] = s1; ed[n][h] = s2;
  }
  if (tid < NN) {
    int i = tid, r = i / GDIM, c = i % GDIM, k = 0;
    for (int dr = -1; dr <= 1; dr++)
      for (int dc = -1; dc <= 1; dc++) {
        if (dr == 0 && dc == 0) continue;
        int rr = r + dr, cc = c + dc;
        if (rr >= 0 && rr < GDIM && cc >= 0 && cc < GDIM)
          srcs[i][k++] = rr * GDIM + cc;
      }
    srcs[i][k++] = knn[((size_t)b * NN + i) * 3 + 0];
    srcs[i][k++] = knn[((size_t)b * NN + i) * 3 + 1];
    srcs[i][k++] = knn[((size_t)b * NN + i) * 3 + 2];
    srcs[i][k++] = i;   // self loop
    cnt[i] = k;
    cnt_g[(size_t)b * NN + i] = k;
    for (int j = 0; j < MAXE; j++)
      srcs_g[((size_t)b * NN + i) * MAXE + j] = srcs[i][j < k ? j : 0];
  }
  __syncthreads();
  for (int p = tid; p < NN * HD; p += 256) {
    int i = p >> 3, h = p & 7;
    int k = cnt[i];
    float e[MAXE];
    float m = -1e30f;
#pragma unroll
    for (int j = 0; j < MAXE; j++) {
      if (j < k) {
        float v = es[srcs[i][j]][h] + ed[i][h];
        v = v >= 0.f ? v : 0.2f * v;   // leaky_relu 0.2
        e[j] = v;
        m = fmaxf(m, v);
      }
    }
    float denom = 0.f;
#pragma unroll
    for (int j = 0; j < MAXE; j++) {
      if (j < k) { e[j] = expf(e[j] - m); denom += e[j]; }
    }
    float inv = 1.f / fmaxf(denom, 1e-16f);
#pragma unroll
    for (int j = 0; j < MAXE; j++) {
      if (j < k)
        alpha_g[(((size_t)b * NN + i) * MAXE + j) * HD + h] = e[j] * inv;
    }
  }
}

// ---------------------------------------------------------------------------
// K4b: attn1 aggregation — block per (graph,node); emits Z1 as bf16 hi/lo
// ---------------------------------------------------------------------------
__global__ void __launch_bounds__(256) attn1_agg(
    const float* __restrict__ H, const int* __restrict__ srcs_g,
    const int* __restrict__ cnt_g, const float* __restrict__ alpha_g,
    const float* __restrict__ b1,
    unsigned short* __restrict__ Zh, unsigned short* __restrict__ Zl) {
  const int bid = blockIdx.x;          // = b*NN + i
  const int b = bid / NN;
  const int tid = threadIdx.x;
  __shared__ float al[MAXE][HD];
  __shared__ int ss[MAXE];
  const int k = cnt_g[bid];
  if (tid < MAXE * HD) al[tid >> 3][tid & 7] = alpha_g[(size_t)bid * MAXE * HD + tid];
  if (tid < MAXE) ss[tid] = srcs_g[(size_t)bid * MAXE + tid];
  __syncthreads();
  const float4* Hb = (const float4*)(H + (size_t)b * NN * FDIM);
  const int h = tid >> 5;
  float4 acc = ((const float4*)b1)[tid];
  for (int j = 0; j < k; j++) {
    float a = al[j][h];
    float4 v = Hb[(size_t)ss[j] * (FDIM / 4) + tid];
    acc.x += a * v.x; acc.y += a * v.y; acc.z += a * v.z; acc.w += a * v.w;
  }
  acc.x = acc.x > 0.f ? acc.x : expm1f(acc.x);
  acc.y = acc.y > 0.f ? acc.y : expm1f(acc.y);
  acc.z = acc.z > 0.f ? acc.z : expm1f(acc.z);
  acc.w = acc.w > 0.f ? acc.w : expm1f(acc.w);
  us4 hv, lv;
  hv.x = f2bf(acc.x); lv.x = f2bf(acc.x - bf2f(hv.x));
  hv.y = f2bf(acc.y); lv.y = f2bf(acc.y - bf2f(hv.y));
  hv.z = f2bf(acc.z); lv.z = f2bf(acc.z - bf2f(hv.z));
  hv.w = f2bf(acc.w); lv.w = f2bf(acc.w - bf2f(hv.w));
  *(us4*)&Zh[(size_t)bid * FDIM + (tid << 2)] = hv;
  *(us4*)&Zl[(size_t)bid * FDIM + (tid << 2)] = lv;
}

// ---------------------------------------------------------------------------
// K6a: attn2 prep — per graph: es/ed (H=1,C=256), softmax alphas
// ---------------------------------------------------------------------------
__global__ void __launch_bounds__(256) attn2_prep(
    const float* __restrict__ H2, const int* __restrict__ srcs_g,
    const int* __restrict__ cnt_g, const float* __restrict__ a_src,
    const float* __restrict__ a_dst, float* __restrict__ alpha_g) {
  const int b = blockIdx.x, tid = threadIdx.x;
  __shared__ float es[NN], ed[NN];
  const float* Hb = H2 + (size_t)b * NN * ODIM;
  if (tid < NN) {
    const float* hr = Hb + (size_t)tid * ODIM;
    float s1 = 0.f, s2 = 0.f;
    for (int c = 0; c < ODIM; c += 4) {
      float4 hv = *(const float4*)&hr[c];
      float4 as = *(const float4*)&a_src[c];
      float4 ad = *(const float4*)&a_dst[c];
      s1 += hv.x*as.x + hv.y*as.y + hv.z*as.z + hv.w*as.w;
      s2 += hv.x*ad.x + hv.y*ad.y + hv.z*ad.z + hv.w*ad.w;
    }
    es[tid] = s1; ed[tid] = s2;
  }
  __syncthreads();
  if (tid < NN) {
    const int i = tid;
    const int k = cnt_g[(size_t)b * NN + i];
    float e[MAXE];
    float m = -1e30f;
#pragma unroll
    for (int j = 0; j < MAXE; j++) {
      if (j < k) {
        int s = srcs_g[((size_t)b * NN + i) * MAXE + j];
        float v = es[s] + ed[i];
        v = v >= 0.f ? v : 0.2f * v;
        e[j] = v;
        m = fmaxf(m, v);
      }
    }
    float denom = 0.f;
#pragma unroll
    for (int j = 0; j < MAXE; j++) {
      if (j < k) { e[j] = expf(e[j] - m); denom += e[j]; }
    }
    float inv = 1.f / fmaxf(denom, 1e-16f);
#pragma unroll
    for (int j = 0; j < MAXE; j++) {
      if (j < k) alpha_g[((size_t)b * NN + i) * MAXE + j] = e[j] * inv;
    }
  }
}

// ---------------------------------------------------------------------------
// K6b: attn2 aggregation — block per (graph,node); thread = channel
// ---------------------------------------------------------------------------
__global__ void __launch_bounds__(256) attn2_agg(
    const float* __restrict__ H2, const int* __restrict__ srcs_g,
    const int* __restrict__ cnt_g, const float* __restrict__ alpha_g,
    const float* __restrict__ b2, float* __restrict__ Z2) {
  const int bid = blockIdx.x;
  const int b = bid / NN;
  const int tid = threadIdx.x;
  __shared__ float al[MAXE];
  __shared__ int ss[MAXE];
  const int k = cnt_g[bid];
  if (tid < MAXE) {
    al[tid] = alpha_g[(size_t)bid * MAXE + tid];
    ss[tid] = srcs_g[(size_t)bid * MAXE + tid];
  }
  __syncthreads();
  const float* Hb = H2 + (size_t)b * NN * ODIM;
  float acc = b2[tid];
  for (int j = 0; j < k; j++)
    acc += al[j] * Hb[(size_t)ss[j] * ODIM + tid];
  acc = acc > 0.f ? acc : expm1f(acc);
  Z2[(size_t)bid * ODIM + tid] = acc;
}

// ---------------------------------------------------------------------------
// K6c: global mean pool
// ---------------------------------------------------------------------------
__global__ void __launch_bounds__(256) pool_kernel(
    const float* __restrict__ Z2, float* __restrict__ pooled) {
  const int b = blockIdx.x, c = threadIdx.x;
  float s = 0.f;
  for (int i = 0; i < NN; i++)
    s += Z2[((size_t)b * NN + i) * ODIM + c];
  pooled[(size_t)b * ODIM + c] = s * (1.f / 49.f);
}

// ---------------------------------------------------------------------------
// K7: classifier
// ---------------------------------------------------------------------------
__global__ void __launch_bounds__(256) classifier_kernel(
    const float* __restrict__ pooled, const float* __restrict__ Wc1,
    const float* __restrict__ bc1, const float* __restrict__ Wc2,
    const float* __restrict__ bc2, float* __restrict__ out) {
  const int b = blockIdx.x, tid = threadIdx.x;
  __shared__ float p[ODIM];
  __shared__ float t[ODIM];
  p[tid] = pooled[(size_t)b * ODIM + tid];
  __syncthreads();
  float a = bc1[tid];
  for (int c = 0; c < ODIM; c++) a += p[c] * Wc1[(size_t)c * ODIM + tid];
  t[tid] = a > 0.f ? a : 0.f;
  __syncthreads();
  if (tid < NC) {
    float o = bc2[tid];
    for (int j = 0; j < ODIM; j++) o += t[j] * Wc2[(size_t)j * NC + tid];
    out[(size_t)b * NC + tid] = o;
  }
}

// ---------------------------------------------------------------------------
extern "C" void kernel_launch(void* const* d_in, const int* in_sizes, int n_in,
                              void* d_out, int out_size, void* d_ws, size_t ws_size,
                              hipStream_t stream) {
  const float* feat   = (const float*)d_in[0];
  const float* W1     = (const float*)d_in[1];
  const float* a_src1 = (const float*)d_in[2];
  const float* a_dst1 = (const float*)d_in[3];
  const float* b1     = (const float*)d_in[4];
  const float* W2     = (const float*)d_in[5];
  const float* a_src2 = (const float*)d_in[6];
  const float* a_dst2 = (const float*)d_in[7];
  const float* b2     = (const float*)d_in[8];
  const float* Wc1    = (const float*)d_in[9];
  const float* bc1    = (const float*)d_in[10];
  const float* Wc2    = (const float*)d_in[11];
  const float* bc2    = (const float*)d_in[12];

  const int B = in_sizes[0] / (FDIM * NN);   // 256
  const int M = B * NN;                       // 12544

  const size_t xE = (size_t)M * FDIM;         // 12,845,056
  float* X  = (float*)d_ws;                   // fp32 X; later H2 (M*ODIM)
  float* H1 = X + xE;                         // fp32 H1; later Z2 (M*ODIM)
  unsigned short* Xh = (unsigned short*)(H1 + xE);  // bf16 hi; later Z1h
  unsigned short* Xl = Xh + xE;                     // bf16 lo; later Z1l
  unsigned short* W1hT = Xl + xE;                   // [1024][1024]
  unsigned short* W1lT = W1hT + (size_t)FDIM * FDIM;
  unsigned short* W2hT = W1lT + (size_t)FDIM * FDIM;  // [256][1024]
  unsigned short* W2lT = W2hT + (size_t)ODIM * FDIM;
  int*   knn    = (int*)(W2lT + (size_t)ODIM * FDIM);
  int*   srcs_g = knn + (size_t)M * 3;
  int*   cnt_g  = srcs_g + (size_t)M * MAXE;
  float* alpha1 = (float*)(cnt_g + M);
  float* alpha2 = alpha1 + (size_t)M * MAXE * HD;
  float* pooled = alpha2 + (size_t)M * MAXE;
  // aliases (producer strictly after last reader of the original)
  float* H2  = X;      // X dead after knn_kernel
  float* Z2  = H1;     // H1 dead after attn1_agg
  unsigned short* Z1h = Xh;  // Xh/Xl dead after gemm1
  unsigned short* Z1l = Xl;

  relu_transpose_kernel<<<B * 16, 256, 0, stream>>>(feat, X, Xh, Xl);
  knn_kernel<<<B * KROWS, 256, 0, stream>>>(X, knn);
  wconvT_kernel<<<(FDIM / 64) * (FDIM / 64), 256, 0, stream>>>(W1, FDIM, FDIM, W1hT, W1lT);
  wconvT_kernel<<<(FDIM / 64) * (ODIM / 64), 256, 0, stream>>>(W2, FDIM, ODIM, W2hT, W2lT);
  // H1 = X @ W1
  gemm_bf16x3<<<(M / 128) * (FDIM / 128), 256, 0, stream>>>(
      Xh, Xl, W1hT, W1lT, H1, M, FDIM, FDIM);
  // attention layer 1 -> Z1 (bf16 hi/lo into Xh/Xl)
  attn1_prep<<<B, 256, 0, stream>>>(H1, knn, a_src1, a_dst1, srcs_g, cnt_g, alpha1);
  attn1_agg<<<M, 256, 0, stream>>>(H1, srcs_g, cnt_g, alpha1, b1, Z1h, Z1l);
  // H2 = Z1 @ W2  (into X buffer)
  gemm_bf16x3<<<(M / 128) * (ODIM / 128), 256, 0, stream>>>(
      Z1h, Z1l, W2hT, W2lT, H2, M, ODIM, FDIM);
  // attention layer 2 -> Z2 (into H1 buffer)
  attn2_prep<<<B, 256, 0, stream>>>(H2, srcs_g, cnt_g, a_src2, a_dst2, alpha2);
  attn2_agg<<<M, 256, 0, stream>>>(H2, srcs_g, cnt_g, alpha2, b2, Z2);
  pool_kernel<<<B, 256, 0, stream>>>(Z2, pooled);
  classifier_kernel<<<B, 256, 0, stream>>>(pooled, Wc1, bc1, Wc2, bc2, (float*)d_out);
}

// Round 6
// 367.894 us; speedup vs baseline: 3.6851x; 1.2964x over previous
//
#include <hip/hip_runtime.h>

#define GDIM 7
#define NN 49            // nodes per graph
#define FDIM 1024
#define HD 8
#define CD 128
#define ODIM 256
#define NC 14
#define MAXE 12          // max incoming edges: 8 spatial + 3 knn + self

typedef __attribute__((ext_vector_type(4))) float f32x4;
typedef __attribute__((ext_vector_type(8))) short s16x8;

struct us4 { unsigned short x, y, z, w; };

__device__ __forceinline__ unsigned short f2bf(float x) {
  unsigned u = __float_as_uint(x);
  return (unsigned short)((u + 0x7fffu + ((u >> 16) & 1u)) >> 16);  // RNE
}
__device__ __forceinline__ float bf2f(unsigned short h) {
  return __uint_as_float((unsigned)h << 16);
}

#define GLOAD_LDS16(g, l)                                          \
  __builtin_amdgcn_global_load_lds(                                \
      (const __attribute__((address_space(1))) void*)(g),          \
      (__attribute__((address_space(3))) void*)(l), 16, 0, 0)

// ---------------------------------------------------------------------------
// K1: relu + transpose  feat[B,1024,49] -> X fp32 + Xh/Xl bf16 split [B*49,1024]
// ---------------------------------------------------------------------------
__global__ void __launch_bounds__(256) relu_transpose_kernel(
    const float* __restrict__ F, float* __restrict__ X,
    unsigned short* __restrict__ Xh, unsigned short* __restrict__ Xl) {
  const int b  = blockIdx.x >> 4;          // 16 f-chunks of 64
  const int f0 = (blockIdx.x & 15) << 6;
  const int tid = threadIdx.x;
  __shared__ float lds[64 * NN];
  const float* src = F + (size_t)b * FDIM * NN + (size_t)f0 * NN;
  for (int idx = tid; idx < 64 * NN; idx += 256) lds[idx] = src[idx];
  __syncthreads();
  for (int pass = 0; pass < 13; pass++) {
    int n = pass * 4 + (tid >> 6);
    int fi = tid & 63;
    if (n < NN) {
      float v = lds[fi * NN + n];
      v = v > 0.f ? v : 0.f;
      size_t o = ((size_t)b * NN + n) * FDIM + f0 + fi;
      X[o] = v;
      unsigned short h = f2bf(v);
      Xh[o] = h;
      Xl[o] = f2bf(v - bf2f(h));
    }
  }
}

// ---------------------------------------------------------------------------
// K2: kNN v3 — register-tiled fp32 Gram (one block per graph).
//   14x14 thread grid, each thread a 4x4 tile with stride-14 rows/cols:
//   rows {tr,tr+14,tr+28,tr+42}, cols {tc,...}. float4 k-blocking:
//   8 ds_read_b128 per 64 FMAs. Diagonal of Gram = |x|^2 (free).
// ---------------------------------------------------------------------------
__global__ void __launch_bounds__(256) knn_kernel(
    const float* __restrict__ X, int* __restrict__ knn) {
  const int b = blockIdx.x, tid = threadIdx.x;
  __shared__ float xs[56][68];     // [rows][64-chunk], stride 68 (b128-aligned)
  __shared__ float gram[56][57];
  const float* Xb = X + (size_t)b * NN * FDIM;

  const int tr = tid / 14, tc = tid % 14;   // active: tid < 196
  float acc[4][4];
#pragma unroll
  for (int i = 0; i < 4; i++)
#pragma unroll
    for (int j = 0; j < 4; j++) acc[i][j] = 0.f;

  for (int c0 = 0; c0 < FDIM; c0 += 64) {
    __syncthreads();
    // stage 49 rows x 16 float4
    for (int idx = tid; idx < NN * 16; idx += 256) {
      int n = idx >> 4, q = idx & 15;
      *(float4*)&xs[n][q << 2] =
          *(const float4*)&Xb[(size_t)n * FDIM + c0 + (q << 2)];
    }
    __syncthreads();
    if (tid < 196) {
#pragma unroll
      for (int k4 = 0; k4 < 64; k4 += 4) {
        float4 a[4], bb[4];
#pragma unroll
        for (int i = 0; i < 4; i++) a[i]  = *(const float4*)&xs[tr + 14 * i][k4];
#pragma unroll
        for (int j = 0; j < 4; j++) bb[j] = *(const float4*)&xs[tc + 14 * j][k4];
#pragma unroll
        for (int i = 0; i < 4; i++)
#pragma unroll
          for (int j = 0; j < 4; j++)
            acc[i][j] += a[i].x * bb[j].x + a[i].y * bb[j].y +
                         a[i].z * bb[j].z + a[i].w * bb[j].w;
      }
    }
  }
  if (tid < 196) {
#pragma unroll
    for (int i = 0; i < 4; i++)
#pragma unroll
      for (int j = 0; j < 4; j++) gram[tr + 14 * i][tc + 14 * j] = acc[i][j];
  }
  __syncthreads();
  if (tid < NN) {
    const int n = tid;
    const float sqn = gram[n][n];
    float d0 = 1e30f, d1 = 1e30f, d2 = 1e30f;
    int i0 = 0, i1 = 0, i2 = 0;
    for (int m = 0; m < NN; m++) {
      if (m == n) continue;
      float d = sqn + gram[m][m] - 2.f * gram[n][m];
      if (d < d0)      { d2=d1; i2=i1; d1=d0; i1=i0; d0=d; i0=m; }
      else if (d < d1) { d2=d1; i2=i1; d1=d;  i1=m; }
      else if (d < d2) { d2=d;  i2=m; }
    }
    knn[((size_t)b * NN + n) * 3 + 0] = i0;
    knn[((size_t)b * NN + n) * 3 + 1] = i1;
    knn[((size_t)b * NN + n) * 3 + 2] = i2;
  }
}

// ---------------------------------------------------------------------------
// K-w: weight convert + transpose  W[K,N] fp32 -> WhT/WlT[N,K] bf16 split
// ---------------------------------------------------------------------------
__global__ void __launch_bounds__(256) wconvT_kernel(
    const float* __restrict__ W, int K, int N,
    unsigned short* __restrict__ WhT, unsigned short* __restrict__ WlT) {
  __shared__ float t[64][65];
  const int nbx = N >> 6;
  const int bx = blockIdx.x % nbx, by = blockIdx.x / nbx;
  const int r0 = by << 6, c0 = bx << 6;
  const int tid = threadIdx.x;
#pragma unroll
  for (int i = 0; i < 16; i++) {
    int r = i * 4 + (tid >> 6), c = tid & 63;
    t[r][c] = W[(size_t)(r0 + r) * N + c0 + c];
  }
  __syncthreads();
#pragma unroll
  for (int i = 0; i < 16; i++) {
    int n = i * 4 + (tid >> 6);   // row of WT (= col of W)
    int k = tid & 63;             // col of WT (= row of W)
    float x = t[k][n];
    unsigned short h = f2bf(x);
    size_t o = (size_t)(c0 + n) * K + r0 + k;
    WhT[o] = h;
    WlT[o] = f2bf(x - bf2f(h));
  }
}

// ---------------------------------------------------------------------------
// K3/K5: bf16x3-split MFMA GEMM  C[M,N] = (Ah+Al)@(Bh+Bl)
//   A as [M,K] bf16 hi/lo, B pre-transposed [N,K] bf16 hi/lo.
//   128x128 tile, BK=32, 4 waves, m97-style global_load_lds staging.
// ---------------------------------------------------------------------------
__global__ void __launch_bounds__(256) gemm_bf16x3(
    const unsigned short* __restrict__ A_h, const unsigned short* __restrict__ A_l,
    const unsigned short* __restrict__ BT_h, const unsigned short* __restrict__ BT_l,
    float* __restrict__ C, int M, int N, int K) {
  __shared__ unsigned short sAh[128][32], sAl[128][32];
  __shared__ unsigned short sBh[128][32], sBl[128][32];
  const int tid = threadIdx.x;
  const int w = tid >> 6, lane = tid & 63;
  const int nbx = N >> 7;
  const int bx = blockIdx.x % nbx, by = blockIdx.x / nbx;
  const int row0 = by << 7, col0 = bx << 7;
  const int wr = (w >> 1) << 6, wc = (w & 1) << 6;   // wave quadrant
  const int srow = lane >> 2, schk = lane & 3;       // staging: row/16B-chunk
  const int fr = lane & 15, fk = (lane >> 4) << 3;   // fragment: row, k-base

  f32x4 acc[4][4];
#pragma unroll
  for (int m = 0; m < 4; m++)
#pragma unroll
    for (int n = 0; n < 4; n++) acc[m][n] = (f32x4){0.f, 0.f, 0.f, 0.f};

  for (int k0 = 0; k0 < K; k0 += 32) {
    __syncthreads();
#pragma unroll
    for (int i = 0; i < 2; i++) {
      const int rbase = (w << 5) + (i << 4);         // wave-uniform segment base
      const int gr = rbase + srow;                   // per-lane row in tile
      const size_t ga = (size_t)(row0 + gr) * K + k0 + (schk << 3);
      GLOAD_LDS16(A_h + ga, &sAh[rbase][0]);
      GLOAD_LDS16(A_l + ga, &sAl[rbase][0]);
      const size_t gb = (size_t)(col0 + gr) * K + k0 + (schk << 3);
      GLOAD_LDS16(BT_h + gb, &sBh[rbase][0]);
      GLOAD_LDS16(BT_l + gb, &sBl[rbase][0]);
    }
    __syncthreads();
    s16x8 ah[4], al[4], bh[4], bl[4];
#pragma unroll
    for (int m = 0; m < 4; m++) {
      ah[m] = *(const s16x8*)&sAh[wr + (m << 4) + fr][fk];
      al[m] = *(const s16x8*)&sAl[wr + (m << 4) + fr][fk];
      bh[m] = *(const s16x8*)&sBh[wc + (m << 4) + fr][fk];
      bl[m] = *(const s16x8*)&sBl[wc + (m << 4) + fr][fk];
    }
#pragma unroll
    for (int m = 0; m < 4; m++)
#pragma unroll
      for (int n = 0; n < 4; n++) {
        acc[m][n] = __builtin_amdgcn_mfma_f32_16x16x32_bf16(ah[m], bh[n], acc[m][n], 0, 0, 0);
        acc[m][n] = __builtin_amdgcn_mfma_f32_16x16x32_bf16(ah[m], bl[n], acc[m][n], 0, 0, 0);
        acc[m][n] = __builtin_amdgcn_mfma_f32_16x16x32_bf16(al[m], bh[n], acc[m][n], 0, 0, 0);
      }
  }
  const int crow = (lane >> 4) << 2, ccol = lane & 15;
#pragma unroll
  for (int m = 0; m < 4; m++)
#pragma unroll
    for (int n = 0; n < 4; n++)
#pragma unroll
      for (int v = 0; v < 4; v++)
        C[(size_t)(row0 + wr + (m << 4) + crow + v) * N + col0 + wc + (n << 4) + ccol] =
            acc[m][n][v];
}

// ---------------------------------------------------------------------------
// K4a: attn1 prep — per graph: es/ed dots, edge lists, softmax alphas
// ---------------------------------------------------------------------------
__global__ void __launch_bounds__(256) attn1_prep(
    const float* __restrict__ H, const int* __restrict__ knn,
    const float* __restrict__ a_src, const float* __restrict__ a_dst,
    int* __restrict__ srcs_g, int* __restrict__ cnt_g,
    float* __restrict__ alpha_g) {
  const int b = blockIdx.x, tid = threadIdx.x;
  __shared__ float es[NN][HD], ed[NN][HD];
  __shared__ int srcs[NN][MAXE];
  __shared__ int cnt[NN];
  const float* Hb = H + (size_t)b * NN * FDIM;

  for (int p = tid; p < NN * HD; p += 256) {
    int n = p >> 3, h = p & 7;
    const float* hr = Hb + (size_t)n * FDIM + h * CD;
    float s1 = 0.f, s2 = 0.f;
    for (int c = 0; c < CD; c += 4) {
      float4 hv = *(const float4*)&hr[c];
      float4 as = *(const float4*)&a_src[h * CD + c];
      float4 ad = *(const float4*)&a_dst[h * CD + c];
      s1 += hv.x*as.x + hv.y*as.y + hv.z*as.z + hv.w*as.w;
      s2 += hv.x*ad.x + hv.y*ad.y + hv.z*ad.z + hv.w*ad.w;
    }
    es[n][h] = s1; ed[n][h] = s2;
  }
  if (tid < NN) {
    int i = tid, r = i / GDIM, c = i % GDIM, k = 0;
    for (int dr = -1; dr <= 1; dr++)
      for (int dc = -1; dc <= 1; dc++) {
        if (dr == 0 && dc == 0) continue;
        int rr = r + dr, cc = c + dc;
        if (rr >= 0 && rr < GDIM && cc >= 0 && cc < GDIM)
          srcs[i][k++] = rr * GDIM + cc;
      }
    srcs[i][k++] = knn[((size_t)b * NN + i) * 3 + 0];
    srcs[i][k++] = knn[((size_t)b * NN + i) * 3 + 1];
    srcs[i][k++] = knn[((size_t)b * NN + i) * 3 + 2];
    srcs[i][k++] = i;   // self loop
    cnt[i] = k;
    cnt_g[(size_t)b * NN + i] = k;
    for (int j = 0; j < MAXE; j++)
      srcs_g[((size_t)b * NN + i) * MAXE + j] = srcs[i][j < k ? j : 0];
  }
  __syncthreads();
  for (int p = tid; p < NN * HD; p += 256) {
    int i = p >> 3, h = p & 7;
    int k = cnt[i];
    float e[MAXE];
    float m = -1e30f;
#pragma unroll
    for (int j = 0; j < MAXE; j++) {
      if (j < k) {
        float v = es[srcs[i][j]][h] + ed[i][h];
        v = v >= 0.f ? v : 0.2f * v;   // leaky_relu 0.2
        e[j] = v;
        m = fmaxf(m, v);
      }
    }
    float denom = 0.f;
#pragma unroll
    for (int j = 0; j < MAXE; j++) {
      if (j < k) { e[j] = expf(e[j] - m); denom += e[j]; }
    }
    float inv = 1.f / fmaxf(denom, 1e-16f);
#pragma unroll
    for (int j = 0; j < MAXE; j++) {
      if (j < k)
        alpha_g[(((size_t)b * NN + i) * MAXE + j) * HD + h] = e[j] * inv;
    }
  }
}

// ---------------------------------------------------------------------------
// K4b: attn1 aggregation — block per (graph,node); emits Z1 as bf16 hi/lo
// ---------------------------------------------------------------------------
__global__ void __launch_bounds__(256) attn1_agg(
    const float* __restrict__ H, const int* __restrict__ srcs_g,
    const int* __restrict__ cnt_g, const float* __restrict__ alpha_g,
    const float* __restrict__ b1,
    unsigned short* __restrict__ Zh, unsigned short* __restrict__ Zl) {
  const int bid = blockIdx.x;          // = b*NN + i
  const int b = bid / NN;
  const int tid = threadIdx.x;
  __shared__ float al[MAXE][HD];
  __shared__ int ss[MAXE];
  const int k = cnt_g[bid];
  if (tid < MAXE * HD) al[tid >> 3][tid & 7] = alpha_g[(size_t)bid * MAXE * HD + tid];
  if (tid < MAXE) ss[tid] = srcs_g[(size_t)bid * MAXE + tid];
  __syncthreads();
  const float4* Hb = (const float4*)(H + (size_t)b * NN * FDIM);
  const int h = tid >> 5;
  float4 acc = ((const float4*)b1)[tid];
  for (int j = 0; j < k; j++) {
    float a = al[j][h];
    float4 v = Hb[(size_t)ss[j] * (FDIM / 4) + tid];
    acc.x += a * v.x; acc.y += a * v.y; acc.z += a * v.z; acc.w += a * v.w;
  }
  acc.x = acc.x > 0.f ? acc.x : expm1f(acc.x);
  acc.y = acc.y > 0.f ? acc.y : expm1f(acc.y);
  acc.z = acc.z > 0.f ? acc.z : expm1f(acc.z);
  acc.w = acc.w > 0.f ? acc.w : expm1f(acc.w);
  us4 hv, lv;
  hv.x = f2bf(acc.x); lv.x = f2bf(acc.x - bf2f(hv.x));
  hv.y = f2bf(acc.y); lv.y = f2bf(acc.y - bf2f(hv.y));
  hv.z = f2bf(acc.z); lv.z = f2bf(acc.z - bf2f(hv.z));
  hv.w = f2bf(acc.w); lv.w = f2bf(acc.w - bf2f(hv.w));
  *(us4*)&Zh[(size_t)bid * FDIM + (tid << 2)] = hv;
  *(us4*)&Zl[(size_t)bid * FDIM + (tid << 2)] = lv;
}

// ---------------------------------------------------------------------------
// K6a: attn2 prep — per graph: es/ed (H=1,C=256), softmax alphas
// ---------------------------------------------------------------------------
__global__ void __launch_bounds__(256) attn2_prep(
    const float* __restrict__ H2, const int* __restrict__ srcs_g,
    const int* __restrict__ cnt_g, const float* __restrict__ a_src,
    const float* __restrict__ a_dst, float* __restrict__ alpha_g) {
  const int b = blockIdx.x, tid = threadIdx.x;
  __shared__ float es[NN], ed[NN];
  const float* Hb = H2 + (size_t)b * NN * ODIM;
  if (tid < NN) {
    const float* hr = Hb + (size_t)tid * ODIM;
    float s1 = 0.f, s2 = 0.f;
    for (int c = 0; c < ODIM; c += 4) {
      float4 hv = *(const float4*)&hr[c];
      float4 as = *(const float4*)&a_src[c];
      float4 ad = *(const float4*)&a_dst[c];
      s1 += hv.x*as.x + hv.y*as.y + hv.z*as.z + hv.w*as.w;
      s2 += hv.x*ad.x + hv.y*ad.y + hv.z*ad.z + hv.w*ad.w;
    }
    es[tid] = s1; ed[tid] = s2;
  }
  __syncthreads();
  if (tid < NN) {
    const int i = tid;
    const int k = cnt_g[(size_t)b * NN + i];
    float e[MAXE];
    float m = -1e30f;
#pragma unroll
    for (int j = 0; j < MAXE; j++) {
      if (j < k) {
        int s = srcs_g[((size_t)b * NN + i) * MAXE + j];
        float v = es[s] + ed[i];
        v = v >= 0.f ? v : 0.2f * v;
        e[j] = v;
        m = fmaxf(m, v);
      }
    }
    float denom = 0.f;
#pragma unroll
    for (int j = 0; j < MAXE; j++) {
      if (j < k) { e[j] = expf(e[j] - m); denom += e[j]; }
    }
    float inv = 1.f / fmaxf(denom, 1e-16f);
#pragma unroll
    for (int j = 0; j < MAXE; j++) {
      if (j < k) alpha_g[((size_t)b * NN + i) * MAXE + j] = e[j] * inv;
    }
  }
}

// ---------------------------------------------------------------------------
// K6b: attn2 aggregation — block per (graph,node); thread = channel
// ---------------------------------------------------------------------------
__global__ void __launch_bounds__(256) attn2_agg(
    const float* __restrict__ H2, const int* __restrict__ srcs_g,
    const int* __restrict__ cnt_g, const float* __restrict__ alpha_g,
    const float* __restrict__ b2, float* __restrict__ Z2) {
  const int bid = blockIdx.x;
  const int b = bid / NN;
  const int tid = threadIdx.x;
  __shared__ float al[MAXE];
  __shared__ int ss[MAXE];
  const int k = cnt_g[bid];
  if (tid < MAXE) {
    al[tid] = alpha_g[(size_t)bid * MAXE + tid];
    ss[tid] = srcs_g[(size_t)bid * MAXE + tid];
  }
  __syncthreads();
  const float* Hb = H2 + (size_t)b * NN * ODIM;
  float acc = b2[tid];
  for (int j = 0; j < k; j++)
    acc += al[j] * Hb[(size_t)ss[j] * ODIM + tid];
  acc = acc > 0.f ? acc : expm1f(acc);
  Z2[(size_t)bid * ODIM + tid] = acc;
}

// ---------------------------------------------------------------------------
// K6c: global mean pool
// ---------------------------------------------------------------------------
__global__ void __launch_bounds__(256) pool_kernel(
    const float* __restrict__ Z2, float* __restrict__ pooled) {
  const int b = blockIdx.x, c = threadIdx.x;
  float s = 0.f;
  for (int i = 0; i < NN; i++)
    s += Z2[((size_t)b * NN + i) * ODIM + c];
  pooled[(size_t)b * ODIM + c] = s * (1.f / 49.f);
}

// ---------------------------------------------------------------------------
// K7: classifier
// ---------------------------------------------------------------------------
__global__ void __launch_bounds__(256) classifier_kernel(
    const float* __restrict__ pooled, const float* __restrict__ Wc1,
    const float* __restrict__ bc1, const float* __restrict__ Wc2,
    const float* __restrict__ bc2, float* __restrict__ out) {
  const int b = blockIdx.x, tid = threadIdx.x;
  __shared__ float p[ODIM];
  __shared__ float t[ODIM];
  p[tid] = pooled[(size_t)b * ODIM + tid];
  __syncthreads();
  float a = bc1[tid];
  for (int c = 0; c < ODIM; c++) a += p[c] * Wc1[(size_t)c * ODIM + tid];
  t[tid] = a > 0.f ? a : 0.f;
  __syncthreads();
  if (tid < NC) {
    float o = bc2[tid];
    for (int j = 0; j < ODIM; j++) o += t[j] * Wc2[(size_t)j * NC + tid];
    out[(size_t)b * NC + tid] = o;
  }
}

// ---------------------------------------------------------------------------
extern "C" void kernel_launch(void* const* d_in, const int* in_sizes, int n_in,
                              void* d_out, int out_size, void* d_ws, size_t ws_size,
                              hipStream_t stream) {
  const float* feat   = (const float*)d_in[0];
  const float* W1     = (const float*)d_in[1];
  const float* a_src1 = (const float*)d_in[2];
  const float* a_dst1 = (const float*)d_in[3];
  const float* b1     = (const float*)d_in[4];
  const float* W2     = (const float*)d_in[5];
  const float* a_src2 = (const float*)d_in[6];
  const float* a_dst2 = (const float*)d_in[7];
  const float* b2     = (const float*)d_in[8];
  const float* Wc1    = (const float*)d_in[9];
  const float* bc1    = (const float*)d_in[10];
  const float* Wc2    = (const float*)d_in[11];
  const float* bc2    = (const float*)d_in[12];

  const int B = in_sizes[0] / (FDIM * NN);   // 256
  const int M = B * NN;                       // 12544

  const size_t xE = (size_t)M * FDIM;         // 12,845,056
  float* X  = (float*)d_ws;                   // fp32 X; later H2 (M*ODIM)
  float* H1 = X + xE;                         // fp32 H1; later Z2 (M*ODIM)
  unsigned short* Xh = (unsigned short*)(H1 + xE);  // bf16 hi; later Z1h
  unsigned short* Xl = Xh + xE;                     // bf16 lo; later Z1l
  unsigned short* W1hT = Xl + xE;                   // [1024][1024]
  unsigned short* W1lT = W1hT + (size_t)FDIM * FDIM;
  unsigned short* W2hT = W1lT + (size_t)FDIM * FDIM;  // [256][1024]
  unsigned short* W2lT = W2hT + (size_t)ODIM * FDIM;
  int*   knn    = (int*)(W2lT + (size_t)ODIM * FDIM);
  int*   srcs_g = knn + (size_t)M * 3;
  int*   cnt_g  = srcs_g + (size_t)M * MAXE;
  float* alpha1 = (float*)(cnt_g + M);
  float* alpha2 = alpha1 + (size_t)M * MAXE * HD;
  float* pooled = alpha2 + (size_t)M * MAXE;
  // aliases (producer strictly after last reader of the original)
  float* H2  = X;      // X dead after knn_kernel
  float* Z2  = H1;     // H1 dead after attn1_agg
  unsigned short* Z1h = Xh;  // Xh/Xl dead after gemm1
  unsigned short* Z1l = Xl;

  relu_transpose_kernel<<<B * 16, 256, 0, stream>>>(feat, X, Xh, Xl);
  knn_kernel<<<B, 256, 0, stream>>>(X, knn);
  wconvT_kernel<<<(FDIM / 64) * (FDIM / 64), 256, 0, stream>>>(W1, FDIM, FDIM, W1hT, W1lT);
  wconvT_kernel<<<(FDIM / 64) * (ODIM / 64), 256, 0, stream>>>(W2, FDIM, ODIM, W2hT, W2lT);
  // H1 = X @ W1
  gemm_bf16x3<<<(M / 128) * (FDIM / 128), 256, 0, stream>>>(
      Xh, Xl, W1hT, W1lT, H1, M, FDIM, FDIM);
  // attention layer 1 -> Z1 (bf16 hi/lo into Xh/Xl)
  attn1_prep<<<B, 256, 0, stream>>>(H1, knn, a_src1, a_dst1, srcs_g, cnt_g, alpha1);
  attn1_agg<<<M, 256, 0, stream>>>(H1, srcs_g, cnt_g, alpha1, b1, Z1h, Z1l);
  // H2 = Z1 @ W2  (into X buffer)
  gemm_bf16x3<<<(M / 128) * (ODIM / 128), 256, 0, stream>>>(
      Z1h, Z1l, W2hT, W2lT, H2, M, ODIM, FDIM);
  // attention layer 2 -> Z2 (into H1 buffer)
  attn2_prep<<<B, 256, 0, stream>>>(H2, srcs_g, cnt_g, a_src2, a_dst2, alpha2);
  attn2_agg<<<M, 256, 0, stream>>>(H2, srcs_g, cnt_g, alpha2, b2, Z2);
  pool_kernel<<<B, 256, 0, stream>>>(Z2, pooled);
  classifier_kernel<<<B, 256, 0, stream>>>(pooled, Wc1, bc1, Wc2, bc2, (float*)d_out);
}

// Round 9
// 325.185 us; speedup vs baseline: 4.1691x; 1.1313x over previous
//
#include <hip/hip_runtime.h>

#define GDIM 7
#define NN 49            // nodes per graph
#define FDIM 1024
#define HD 8
#define CD 128
#define ODIM 256
#define NC 14
#define MAXE 12          // max incoming edges: 8 spatial + 3 knn + self

typedef __attribute__((ext_vector_type(4))) float f32x4;
typedef __attribute__((ext_vector_type(8))) short s16x8;

struct us4 { unsigned short x, y, z, w; };

__device__ __forceinline__ unsigned short f2bf(float x) {
  unsigned u = __float_as_uint(x);
  return (unsigned short)((u + 0x7fffu + ((u >> 16) & 1u)) >> 16);  // RNE
}
__device__ __forceinline__ float bf2f(unsigned short h) {
  return __uint_as_float((unsigned)h << 16);
}

#define GLOAD_LDS16(g, l)                                          \
  __builtin_amdgcn_global_load_lds(                                \
      (const __attribute__((address_space(1))) void*)(g),          \
      (__attribute__((address_space(3))) void*)(l), 16, 0, 0)

// ---------------------------------------------------------------------------
// K1: relu + transpose  feat[B,1024,49] -> X fp32 + Xh/Xl bf16 split [B*49,1024]
// ---------------------------------------------------------------------------
__global__ void __launch_bounds__(256) relu_transpose_kernel(
    const float* __restrict__ F, float* __restrict__ X,
    unsigned short* __restrict__ Xh, unsigned short* __restrict__ Xl) {
  const int b  = blockIdx.x >> 4;          // 16 f-chunks of 64
  const int f0 = (blockIdx.x & 15) << 6;
  const int tid = threadIdx.x;
  __shared__ float lds[64 * NN];
  const float* src = F + (size_t)b * FDIM * NN + (size_t)f0 * NN;
  for (int idx = tid; idx < 64 * NN; idx += 256) lds[idx] = src[idx];
  __syncthreads();
  for (int pass = 0; pass < 13; pass++) {
    int n = pass * 4 + (tid >> 6);
    int fi = tid & 63;
    if (n < NN) {
      float v = lds[fi * NN + n];
      v = v > 0.f ? v : 0.f;
      size_t o = ((size_t)b * NN + n) * FDIM + f0 + fi;
      X[o] = v;
      unsigned short h = f2bf(v);
      Xh[o] = h;
      Xl[o] = f2bf(v - bf2f(h));
    }
  }
}

// ---------------------------------------------------------------------------
// K2: kNN — register-tiled fp32 Gram (one block per graph), 14x14 threads,
//     each a 4x4 tile (stride-14). Diagonal = |x|^2.
// ---------------------------------------------------------------------------
__global__ void __launch_bounds__(256) knn_kernel(
    const float* __restrict__ X, int* __restrict__ knn) {
  const int b = blockIdx.x, tid = threadIdx.x;
  __shared__ float xs[56][68];
  __shared__ float gram[56][57];
  const float* Xb = X + (size_t)b * NN * FDIM;

  const int tr = tid / 14, tc = tid % 14;   // active: tid < 196
  float acc[4][4];
#pragma unroll
  for (int i = 0; i < 4; i++)
#pragma unroll
    for (int j = 0; j < 4; j++) acc[i][j] = 0.f;

  for (int c0 = 0; c0 < FDIM; c0 += 64) {
    __syncthreads();
    for (int idx = tid; idx < NN * 16; idx += 256) {
      int n = idx >> 4, q = idx & 15;
      *(float4*)&xs[n][q << 2] =
          *(const float4*)&Xb[(size_t)n * FDIM + c0 + (q << 2)];
    }
    __syncthreads();
    if (tid < 196) {
#pragma unroll
      for (int k4 = 0; k4 < 64; k4 += 4) {
        float4 a[4], bb[4];
#pragma unroll
        for (int i = 0; i < 4; i++) a[i]  = *(const float4*)&xs[tr + 14 * i][k4];
#pragma unroll
        for (int j = 0; j < 4; j++) bb[j] = *(const float4*)&xs[tc + 14 * j][k4];
#pragma unroll
        for (int i = 0; i < 4; i++)
#pragma unroll
          for (int j = 0; j < 4; j++)
            acc[i][j] += a[i].x * bb[j].x + a[i].y * bb[j].y +
                         a[i].z * bb[j].z + a[i].w * bb[j].w;
      }
    }
  }
  if (tid < 196) {
#pragma unroll
    for (int i = 0; i < 4; i++)
#pragma unroll
      for (int j = 0; j < 4; j++) gram[tr + 14 * i][tc + 14 * j] = acc[i][j];
  }
  __syncthreads();
  if (tid < NN) {
    const int n = tid;
    const float sqn = gram[n][n];
    float d0 = 1e30f, d1 = 1e30f, d2 = 1e30f;
    int i0 = 0, i1 = 0, i2 = 0;
    for (int m = 0; m < NN; m++) {
      if (m == n) continue;
      float d = sqn + gram[m][m] - 2.f * gram[n][m];
      if (d < d0)      { d2=d1; i2=i1; d1=d0; i1=i0; d0=d; i0=m; }
      else if (d < d1) { d2=d1; i2=i1; d1=d;  i1=m; }
      else if (d < d2) { d2=d;  i2=m; }
    }
    knn[((size_t)b * NN + n) * 3 + 0] = i0;
    knn[((size_t)b * NN + n) * 3 + 1] = i1;
    knn[((size_t)b * NN + n) * 3 + 2] = i2;
  }
}

// ---------------------------------------------------------------------------
// K-w: weight convert + transpose  W[K,N] fp32 -> WhT/WlT[N,K] bf16 split
// ---------------------------------------------------------------------------
__global__ void __launch_bounds__(256) wconvT_kernel(
    const float* __restrict__ W, int K, int N,
    unsigned short* __restrict__ WhT, unsigned short* __restrict__ WlT) {
  __shared__ float t[64][65];
  const int nbx = N >> 6;
  const int bx = blockIdx.x % nbx, by = blockIdx.x / nbx;
  const int r0 = by << 6, c0 = bx << 6;
  const int tid = threadIdx.x;
#pragma unroll
  for (int i = 0; i < 16; i++) {
    int r = i * 4 + (tid >> 6), c = tid & 63;
    t[r][c] = W[(size_t)(r0 + r) * N + c0 + c];
  }
  __syncthreads();
#pragma unroll
  for (int i = 0; i < 16; i++) {
    int n = i * 4 + (tid >> 6);   // row of WT (= col of W)
    int k = tid & 63;             // col of WT (= row of W)
    float x = t[k][n];
    unsigned short h = f2bf(x);
    size_t o = (size_t)(c0 + n) * K + r0 + k;
    WhT[o] = h;
    WlT[o] = f2bf(x - bf2f(h));
  }
}

// ---------------------------------------------------------------------------
// K3/K5: bf16x3-split MFMA GEMM, 128x128 tile, BK=64, 4 waves.
//   + bijective XCD blockIdx swizzle (A-panel L2 locality)
//   + XOR chunk swizzle: linear LDS dest, pre-swizzled global src,
//     swizzled ds_read (16B chunk ^= row&7) -> even bank load.
// ---------------------------------------------------------------------------
__global__ void __launch_bounds__(256) gemm_bf16x3(
    const unsigned short* __restrict__ A_h, const unsigned short* __restrict__ A_l,
    const unsigned short* __restrict__ BT_h, const unsigned short* __restrict__ BT_l,
    float* __restrict__ C, int M, int N, int K) {
  __shared__ unsigned short sAh[128][64], sAl[128][64];
  __shared__ unsigned short sBh[128][64], sBl[128][64];
  const int tid = threadIdx.x;
  const int w = tid >> 6, lane = tid & 63;
  const int nbx = N >> 7;
  // bijective XCD swizzle (m204): physical xcd = blockIdx%8 gets a
  // contiguous chunk of logical tiles -> consecutive tiles (sharing an
  // A-panel) stay on one XCD's L2.
  const int nwg = gridDim.x;
  const int q = nwg >> 3, r = nwg & 7;
  const int xcd = blockIdx.x & 7, loc = blockIdx.x >> 3;
  const int wg = (xcd < r) ? (xcd * (q + 1) + loc)
                           : (r * (q + 1) + (xcd - r) * q + loc);
  const int bx = wg % nbx, by = wg / nbx;
  const int row0 = by << 7, col0 = bx << 7;
  const int wr = (w >> 1) << 6, wc = (w & 1) << 6;   // wave quadrant
  const int sgr = lane >> 3;        // staging: row within 8-row stripe
  const int schunk = lane & 7;      // staging: 16B chunk slot (LDS side)
  const int fr = lane & 15;         // fragment row
  const int fq = lane >> 4;         // fragment k-quarter (0..3)

  f32x4 acc[4][4];
#pragma unroll
  for (int m = 0; m < 4; m++)
#pragma unroll
    for (int n = 0; n < 4; n++) acc[m][n] = (f32x4){0.f, 0.f, 0.f, 0.f};

  for (int k0 = 0; k0 < K; k0 += 64) {
    __syncthreads();
#pragma unroll
    for (int i = 0; i < 4; i++) {
      const int rbase = (w << 5) + (i << 3);      // wave-uniform 8-row stripe
      const int gr = rbase + sgr;
      const int sc = schunk ^ (gr & 7);           // pre-swizzled global chunk
      const size_t ga = (size_t)(row0 + gr) * K + k0 + (sc << 3);
      GLOAD_LDS16(A_h + ga, &sAh[rbase][0]);
      GLOAD_LDS16(A_l + ga, &sAl[rbase][0]);
      const size_t gb = (size_t)(col0 + gr) * K + k0 + (sc << 3);
      GLOAD_LDS16(BT_h + gb, &sBh[rbase][0]);
      GLOAD_LDS16(BT_l + gb, &sBl[rbase][0]);
    }
    __syncthreads();
#pragma unroll
    for (int ks = 0; ks < 2; ks++) {
      const int cb = (ks << 2) + fq;              // global 16B chunk wanted
      s16x8 ah[4], al[4], bh[4], bl[4];
#pragma unroll
      for (int m = 0; m < 4; m++) {
        const int ra = wr + (m << 4) + fr;
        const int ca = (cb ^ (ra & 7)) << 3;      // swizzled LDS column
        ah[m] = *(const s16x8*)&sAh[ra][ca];
        al[m] = *(const s16x8*)&sAl[ra][ca];
        const int rb = wc + (m << 4) + fr;
        const int cbn = (cb ^ (rb & 7)) << 3;
        bh[m] = *(const s16x8*)&sBh[rb][cbn];
        bl[m] = *(const s16x8*)&sBl[rb][cbn];
      }
#pragma unroll
      for (int m = 0; m < 4; m++)
#pragma unroll
        for (int n = 0; n < 4; n++) {
          acc[m][n] = __builtin_amdgcn_mfma_f32_16x16x32_bf16(ah[m], bh[n], acc[m][n], 0, 0, 0);
          acc[m][n] = __builtin_amdgcn_mfma_f32_16x16x32_bf16(ah[m], bl[n], acc[m][n], 0, 0, 0);
          acc[m][n] = __builtin_amdgcn_mfma_f32_16x16x32_bf16(al[m], bh[n], acc[m][n], 0, 0, 0);
        }
    }
  }
  const int crow = fq << 2, ccol = fr;
#pragma unroll
  for (int m = 0; m < 4; m++)
#pragma unroll
    for (int n = 0; n < 4; n++)
#pragma unroll
      for (int v = 0; v < 4; v++)
        C[(size_t)(row0 + wr + (m << 4) + crow + v) * N + col0 + wc + (n << 4) + ccol] =
            acc[m][n][v];
}

// ---------------------------------------------------------------------------
// K4a: attn1 prep — per graph: es/ed dots, edge lists, softmax alphas
// ---------------------------------------------------------------------------
__global__ void __launch_bounds__(256) attn1_prep(
    const float* __restrict__ H, const int* __restrict__ knn,
    const float* __restrict__ a_src, const float* __restrict__ a_dst,
    int* __restrict__ srcs_g, int* __restrict__ cnt_g,
    float* __restrict__ alpha_g) {
  const int b = blockIdx.x, tid = threadIdx.x;
  __shared__ float es[NN][HD], ed[NN][HD];
  __shared__ int srcs[NN][MAXE];
  __shared__ int cnt[NN];
  const float* Hb = H + (size_t)b * NN * FDIM;

  for (int p = tid; p < NN * HD; p += 256) {
    int n = p >> 3, h = p & 7;
    const float* hr = Hb + (size_t)n * FDIM + h * CD;
    float s1 = 0.f, s2 = 0.f;
    for (int c = 0; c < CD; c += 4) {
      float4 hv = *(const float4*)&hr[c];
      float4 as = *(const float4*)&a_src[h * CD + c];
      float4 ad = *(const float4*)&a_dst[h * CD + c];
      s1 += hv.x*as.x + hv.y*as.y + hv.z*as.z + hv.w*as.w;
      s2 += hv.x*ad.x + hv.y*ad.y + hv.z*ad.z + hv.w*ad.w;
    }
    es[n][h] = s1; ed[n][h] = s2;
  }
  if (tid < NN) {
    int i = tid, r = i / GDIM, c = i % GDIM, k = 0;
    for (int dr = -1; dr <= 1; dr++)
      for (int dc = -1; dc <= 1; dc++) {
        if (dr == 0 && dc == 0) continue;
        int rr = r + dr, cc = c + dc;
        if (rr >= 0 && rr < GDIM && cc >= 0 && cc < GDIM)
          srcs[i][k++] = rr * GDIM + cc;
      }
    srcs[i][k++] = knn[((size_t)b * NN + i) * 3 + 0];
    srcs[i][k++] = knn[((size_t)b * NN + i) * 3 + 1];
    srcs[i][k++] = knn[((size_t)b * NN + i) * 3 + 2];
    srcs[i][k++] = i;   // self loop
    cnt[i] = k;
    cnt_g[(size_t)b * NN + i] = k;
    for (int j = 0; j < MAXE; j++)
      srcs_g[((size_t)b * NN + i) * MAXE + j] = srcs[i][j < k ? j : 0];
  }
  __syncthreads();
  for (int p = tid; p < NN * HD; p += 256) {
    int i = p >> 3, h = p & 7;
    int k = cnt[i];
    float e[MAXE];
    float m = -1e30f;
#pragma unroll
    for (int j = 0; j < MAXE; j++) {
      if (j < k) {
        float v = es[srcs[i][j]][h] + ed[i][h];
        v = v >= 0.f ? v : 0.2f * v;   // leaky_relu 0.2
        e[j] = v;
        m = fmaxf(m, v);
      }
    }
    float denom = 0.f;
#pragma unroll
    for (int j = 0; j < MAXE; j++) {
      if (j < k) { e[j] = expf(e[j] - m); denom += e[j]; }
    }
    float inv = 1.f / fmaxf(denom, 1e-16f);
#pragma unroll
    for (int j = 0; j < MAXE; j++) {
      if (j < k)
        alpha_g[(((size_t)b * NN + i) * MAXE + j) * HD + h] = e[j] * inv;
    }
  }
}

// ---------------------------------------------------------------------------
// K4b: attn1 aggregation — block per (graph,node); emits Z1 as bf16 hi/lo
// ---------------------------------------------------------------------------
__global__ void __launch_bounds__(256) attn1_agg(
    const float* __restrict__ H, const int* __restrict__ srcs_g,
    const int* __restrict__ cnt_g, const float* __restrict__ alpha_g,
    const float* __restrict__ b1,
    unsigned short* __restrict__ Zh, unsigned short* __restrict__ Zl) {
  const int bid = blockIdx.x;          // = b*NN + i
  const int b = bid / NN;
  const int tid = threadIdx.x;
  __shared__ float al[MAXE][HD];
  __shared__ int ss[MAXE];
  const int k = cnt_g[bid];
  if (tid < MAXE * HD) al[tid >> 3][tid & 7] = alpha_g[(size_t)bid * MAXE * HD + tid];
  if (tid < MAXE) ss[tid] = srcs_g[(size_t)bid * MAXE + tid];
  __syncthreads();
  const float4* Hb = (const float4*)(H + (size_t)b * NN * FDIM);
  const int h = tid >> 5;
  float4 acc = ((const float4*)b1)[tid];
  for (int j = 0; j < k; j++) {
    float a = al[j][h];
    float4 v = Hb[(size_t)ss[j] * (FDIM / 4) + tid];
    acc.x += a * v.x; acc.y += a * v.y; acc.z += a * v.z; acc.w += a * v.w;
  }
  acc.x = acc.x > 0.f ? acc.x : expm1f(acc.x);
  acc.y = acc.y > 0.f ? acc.y : expm1f(acc.y);
  acc.z = acc.z > 0.f ? acc.z : expm1f(acc.z);
  acc.w = acc.w > 0.f ? acc.w : expm1f(acc.w);
  us4 hv, lv;
  hv.x = f2bf(acc.x); lv.x = f2bf(acc.x - bf2f(hv.x));
  hv.y = f2bf(acc.y); lv.y = f2bf(acc.y - bf2f(hv.y));
  hv.z = f2bf(acc.z); lv.z = f2bf(acc.z - bf2f(hv.z));
  hv.w = f2bf(acc.w); lv.w = f2bf(acc.w - bf2f(hv.w));
  *(us4*)&Zh[(size_t)bid * FDIM + (tid << 2)] = hv;
  *(us4*)&Zl[(size_t)bid * FDIM + (tid << 2)] = lv;
}

// ---------------------------------------------------------------------------
// K6a: attn2 prep — per graph: es/ed (H=1,C=256), softmax alphas
// ---------------------------------------------------------------------------
__global__ void __launch_bounds__(256) attn2_prep(
    const float* __restrict__ H2, const int* __restrict__ srcs_g,
    const int* __restrict__ cnt_g, const float* __restrict__ a_src,
    const float* __restrict__ a_dst, float* __restrict__ alpha_g) {
  const int b = blockIdx.x, tid = threadIdx.x;
  __shared__ float es[NN], ed[NN];
  const float* Hb = H2 + (size_t)b * NN * ODIM;
  if (tid < NN) {
    const float* hr = Hb + (size_t)tid * ODIM;
    float s1 = 0.f, s2 = 0.f;
    for (int c = 0; c < ODIM; c += 4) {
      float4 hv = *(const float4*)&hr[c];
      float4 as = *(const float4*)&a_src[c];
      float4 ad = *(const float4*)&a_dst[c];
      s1 += hv.x*as.x + hv.y*as.y + hv.z*as.z + hv.w*as.w;
      s2 += hv.x*ad.x + hv.y*ad.y + hv.z*ad.z + hv.w*ad.w;
    }
    es[tid] = s1; ed[tid] = s2;
  }
  __syncthreads();
  if (tid < NN) {
    const int i = tid;
    const int k = cnt_g[(size_t)b * NN + i];
    float e[MAXE];
    float m = -1e30f;
#pragma unroll
    for (int j = 0; j < MAXE; j++) {
      if (j < k) {
        int s = srcs_g[((size_t)b * NN + i) * MAXE + j];
        float v = es[s] + ed[i];
        v = v >= 0.f ? v : 0.2f * v;
        e[j] = v;
        m = fmaxf(m, v);
      }
    }
    float denom = 0.f;
#pragma unroll
    for (int j = 0; j < MAXE; j++) {
      if (j < k) { e[j] = expf(e[j] - m); denom += e[j]; }
    }
    float inv = 1.f / fmaxf(denom, 1e-16f);
#pragma unroll
    for (int j = 0; j < MAXE; j++) {
      if (j < k) alpha_g[((size_t)b * NN + i) * MAXE + j] = e[j] * inv;
    }
  }
}

// ---------------------------------------------------------------------------
// K6b: attn2 aggregation — block per (graph,node); thread = channel
// ---------------------------------------------------------------------------
__global__ void __launch_bounds__(256) attn2_agg(
    const float* __restrict__ H2, const int* __restrict__ srcs_g,
    const int* __restrict__ cnt_g, const float* __restrict__ alpha_g,
    const float* __restrict__ b2, float* __restrict__ Z2) {
  const int bid = blockIdx.x;
  const int b = bid / NN;
  const int tid = threadIdx.x;
  __shared__ float al[MAXE];
  __shared__ int ss[MAXE];
  const int k = cnt_g[bid];
  if (tid < MAXE) {
    al[tid] = alpha_g[(size_t)bid * MAXE + tid];
    ss[tid] = srcs_g[(size_t)bid * MAXE + tid];
  }
  __syncthreads();
  const float* Hb = H2 + (size_t)b * NN * ODIM;
  float acc = b2[tid];
  for (int j = 0; j < k; j++)
    acc += al[j] * Hb[(size_t)ss[j] * ODIM + tid];
  acc = acc > 0.f ? acc : expm1f(acc);
  Z2[(size_t)bid * ODIM + tid] = acc;
}

// ---------------------------------------------------------------------------
// K6c: global mean pool
// ---------------------------------------------------------------------------
__global__ void __launch_bounds__(256) pool_kernel(
    const float* __restrict__ Z2, float* __restrict__ pooled) {
  const int b = blockIdx.x, c = threadIdx.x;
  float s = 0.f;
  for (int i = 0; i < NN; i++)
    s += Z2[((size_t)b * NN + i) * ODIM + c];
  pooled[(size_t)b * ODIM + c] = s * (1.f / 49.f);
}

// ---------------------------------------------------------------------------
// K7: classifier
// ---------------------------------------------------------------------------
__global__ void __launch_bounds__(256) classifier_kernel(
    const float* __restrict__ pooled, const float* __restrict__ Wc1,
    const float* __restrict__ bc1, const float* __restrict__ Wc2,
    const float* __restrict__ bc2, float* __restrict__ out) {
  const int b = blockIdx.x, tid = threadIdx.x;
  __shared__ float p[ODIM];
  __shared__ float t[ODIM];
  p[tid] = pooled[(size_t)b * ODIM + tid];
  __syncthreads();
  float a = bc1[tid];
  for (int c = 0; c < ODIM; c++) a += p[c] * Wc1[(size_t)c * ODIM + tid];
  t[tid] = a > 0.f ? a : 0.f;
  __syncthreads();
  if (tid < NC) {
    float o = bc2[tid];
    for (int j = 0; j < ODIM; j++) o += t[j] * Wc2[(size_t)j * NC + tid];
    out[(size_t)b * NC + tid] = o;
  }
}

// ---------------------------------------------------------------------------
extern "C" void kernel_launch(void* const* d_in, const int* in_sizes, int n_in,
                              void* d_out, int out_size, void* d_ws, size_t ws_size,
                              hipStream_t stream) {
  const float* feat   = (const float*)d_in[0];
  const float* W1     = (const float*)d_in[1];
  const float* a_src1 = (const float*)d_in[2];
  const float* a_dst1 = (const float*)d_in[3];
  const float* b1     = (const float*)d_in[4];
  const float* W2     = (const float*)d_in[5];
  const float* a_src2 = (const float*)d_in[6];
  const float* a_dst2 = (const float*)d_in[7];
  const float* b2     = (const float*)d_in[8];
  const float* Wc1    = (const float*)d_in[9];
  const float* bc1    = (const float*)d_in[10];
  const float* Wc2    = (const float*)d_in[11];
  const float* bc2    = (const float*)d_in[12];

  const int B = in_sizes[0] / (FDIM * NN);   // 256
  const int M = B * NN;                       // 12544

  const size_t xE = (size_t)M * FDIM;         // 12,845,056
  float* X  = (float*)d_ws;                   // fp32 X; later H2 (M*ODIM)
  float* H1 = X + xE;                         // fp32 H1; later Z2 (M*ODIM)
  unsigned short* Xh = (unsigned short*)(H1 + xE);  // bf16 hi; later Z1h
  unsigned short* Xl = Xh + xE;                     // bf16 lo; later Z1l
  unsigned short* W1hT = Xl + xE;                   // [1024][1024]
  unsigned short* W1lT = W1hT + (size_t)FDIM * FDIM;
  unsigned short* W2hT = W1lT + (size_t)FDIM * FDIM;  // [256][1024]
  unsigned short* W2lT = W2hT + (size_t)ODIM * FDIM;
  int*   knn    = (int*)(W2lT + (size_t)ODIM * FDIM);
  int*   srcs_g = knn + (size_t)M * 3;
  int*   cnt_g  = srcs_g + (size_t)M * MAXE;
  float* alpha1 = (float*)(cnt_g + M);
  float* alpha2 = alpha1 + (size_t)M * MAXE * HD;
  float* pooled = alpha2 + (size_t)M * MAXE;
  // aliases (producer strictly after last reader of the original)
  float* H2  = X;      // X dead after knn_kernel
  float* Z2  = H1;     // H1 dead after attn1_agg
  unsigned short* Z1h = Xh;  // Xh/Xl dead after gemm1
  unsigned short* Z1l = Xl;

  relu_transpose_kernel<<<B * 16, 256, 0, stream>>>(feat, X, Xh, Xl);
  knn_kernel<<<B, 256, 0, stream>>>(X, knn);
  wconvT_kernel<<<(FDIM / 64) * (FDIM / 64), 256, 0, stream>>>(W1, FDIM, FDIM, W1hT, W1lT);
  wconvT_kernel<<<(FDIM / 64) * (ODIM / 64), 256, 0, stream>>>(W2, FDIM, ODIM, W2hT, W2lT);
  // H1 = X @ W1
  gemm_bf16x3<<<(M / 128) * (FDIM / 128), 256, 0, stream>>>(
      Xh, Xl, W1hT, W1lT, H1, M, FDIM, FDIM);
  // attention layer 1 -> Z1 (bf16 hi/lo into Xh/Xl)
  attn1_prep<<<B, 256, 0, stream>>>(H1, knn, a_src1, a_dst1, srcs_g, cnt_g, alpha1);
  attn1_agg<<<M, 256, 0, stream>>>(H1, srcs_g, cnt_g, alpha1, b1, Z1h, Z1l);
  // H2 = Z1 @ W2  (into X buffer)
  gemm_bf16x3<<<(M / 128) * (ODIM / 128), 256, 0, stream>>>(
      Z1h, Z1l, W2hT, W2lT, H2, M, ODIM, FDIM);
  // attention layer 2 -> Z2 (into H1 buffer)
  attn2_prep<<<B, 256, 0, stream>>>(H2, srcs_g, cnt_g, a_src2, a_dst2, alpha2);
  attn2_agg<<<M, 256, 0, stream>>>(H2, srcs_g, cnt_g, alpha2, b2, Z2);
  pool_kernel<<<B, 256, 0, stream>>>(Z2, pooled);
  classifier_kernel<<<B, 256, 0, stream>>>(pooled, Wc1, bc1, Wc2, bc2, (float*)d_out);
}